// Round 2
// baseline (1505.132 us; speedup 1.0000x reference)
//
#include <hip/hip_runtime.h>
#include <math.h>

#define BB  16
#define TT  1024
#define NN  128
#define WIN 30
#define NWD 498          // number of windows
#define DM  256          // D_MODEL
#define IND 384          // 3*N

#define INV_W (1.0f/498.0f)

// swizzled LDS row: 16 groups of 8 floats, each group padded to 12 floats
// phys(c) = (c>>3)*12 + (c&7); row stride 192 floats (768 B, %128B==0)
#define ROWF 192

// workspace offsets in floats
#define OFF_MU    0
#define OFF_RSTD  (OFF_MU   + BB*NWD*NN)
#define OFF_SUMLO (OFF_RSTD + BB*NWD*NN)
#define OFF_CM2   (OFF_SUMLO + BB*NN*NN)
#define OFF_CM4   (OFF_CM2  + BB*NN*NN)
#define OFF_CM8   (OFF_CM4  + BB*NN*NN)
#define OFF_ASUM  (OFF_CM8  + BB*NN*NN)
#define OFF_ANORM (OFF_ASUM + BB*NN*NN)
#define OFF_X     (OFF_ANORM + BB*NN*NN)
#define OFF_BUFA  (OFF_X    + BB*NN*IND)
#define OFF_BUFB  (OFF_BUFA + BB*NN*DM)

// ---------------------------------------------------------------- K1: per-window channel stats
__global__ __launch_bounds__(128) void k1_stats(const float* __restrict__ x, float* __restrict__ ws) {
    int bw = blockIdx.x;            // b*NWD + w
    int b = bw / NWD, w = bw - b*NWD;
    int n = threadIdx.x;
    int s = w * 2;
    const float* xp = x + ((size_t)(b*TT + s))*NN + n;
    float sum = 0.f;
#pragma unroll
    for (int t = 0; t < WIN; ++t) sum += xp[t*NN];
    float mean = sum * (1.0f/30.0f);
    float ss = 0.f;
#pragma unroll
    for (int t = 0; t < WIN; ++t) { float d = xp[t*NN] - mean; ss += d*d; }
    float var = fmaxf(ss * (1.0f/29.0f), 1e-8f);
    float r = 1.0f / sqrtf(var);
    ws[OFF_MU   + bw*NN + n] = mean;
    // fold 1/sqrt(29) so corr(i,j) = sum_t y_i y_j directly
    ws[OFF_RSTD + bw*NN + n] = r * 0.185695338f;
}

// stage one normalized window (30 x 128) into swizzled LDS; blockDim must be 256
__device__ __forceinline__ void stage_window(const float* __restrict__ x, const float* __restrict__ ws,
                                             int b, int w, int tid, float* __restrict__ y) {
    int s = w * 2;
    const float4* xr  = (const float4*)(x + (size_t)(b*TT + s)*NN);
    const float4* mu4 = (const float4*)(ws + OFF_MU   + (size_t)(b*NWD + w)*NN);
    const float4* rs4 = (const float4*)(ws + OFF_RSTD + (size_t)(b*NWD + w)*NN);
    for (int idx = tid; idx < WIN*32; idx += 256) {
        int t = idx >> 5, c4 = idx & 31;
        float4 xv = xr[t*32 + c4];
        float4 m  = mu4[c4];
        float4 rv = rs4[c4];
        float4 o;
        o.x = (xv.x - m.x) * rv.x;
        o.y = (xv.y - m.y) * rv.y;
        o.z = (xv.z - m.z) * rv.z;
        o.w = (xv.w - m.w) * rv.w;
        int phys = t*ROWF + (c4 >> 1)*12 + (c4 & 1)*4;
        *(float4*)&y[phys] = o;
    }
}

// ---------------------------------------------------------------- K2: sum of corr over windows
// chunk = 8 windows, grid = BB*63, 8x8 thread tiles over full 128x128
__global__ __launch_bounds__(256, 4) void k2_sumcorr(const float* __restrict__ x, float* __restrict__ ws) {
    __shared__ __align__(16) float y[WIN*ROWF];
    int bx = blockIdx.x;
    int b = bx / 63, wc = bx % 63;
    int w0 = wc*8, w1 = min(NWD, w0+8);
    int tid = threadIdx.x;
    int gi = tid >> 4, gj = tid & 15;            // 8-float group indices
    float acc[8][8];
#pragma unroll
    for (int p=0;p<8;++p)
#pragma unroll
        for (int q=0;q<8;++q) acc[p][q] = 0.f;

    for (int w = w0; w < w1; ++w) {
        __syncthreads();
        stage_window(x, ws, b, w, tid, y);
        __syncthreads();
#pragma unroll 6
        for (int t = 0; t < WIN; ++t) {
            const float* row = &y[t*ROWF];
            float4 a0 = *(const float4*)&row[12*gi];
            float4 a1 = *(const float4*)&row[12*gi+4];
            float4 b0 = *(const float4*)&row[12*gj];
            float4 b1 = *(const float4*)&row[12*gj+4];
            float av[8] = {a0.x,a0.y,a0.z,a0.w,a1.x,a1.y,a1.z,a1.w};
            float bv[8] = {b0.x,b0.y,b0.z,b0.w,b1.x,b1.y,b1.z,b1.w};
#pragma unroll
            for (int p=0;p<8;++p)
#pragma unroll
                for (int q=0;q<8;++q) acc[p][q] = fmaf(av[p], bv[q], acc[p][q]);
        }
    }
    float nwf = (float)(w1 - w0);
    float* sl = ws + OFF_SUMLO + (size_t)b*NN*NN;
    int i0 = gi*8, j0 = gj*8;
#pragma unroll
    for (int p=0;p<8;++p)
#pragma unroll
        for (int q=0;q<8;++q) {
            int ii = i0+p, jj = j0+q;
            float v = (ii==jj) ? nwf : acc[p][q];   // diag of corr is forced to 1 per window
            atomicAdd(&sl[ii*NN+jj], v);
        }
}

// ---------------------------------------------------------------- K4: centered moments d=2,4,8
// chunk = 16 windows, 2 row-halves/block, grid = BB*32*2; 4x8 thread tiles (64x128 per block)
__global__ __launch_bounds__(256, 2) void k4_moments(const float* __restrict__ x, float* __restrict__ ws) {
    __shared__ __align__(16) float y[WIN*ROWF];
    int bx = blockIdx.x;
    int b  = bx >> 6;                 // / 64
    int rem = bx & 63;
    int wc = rem >> 1, ih = rem & 1;
    int w0 = wc*16, w1 = min(NWD, w0+16);
    int tid = threadIdx.x;
    int i0 = ih*64 + (tid >> 4)*4;    // 4 rows
    int gj = tid & 15;                // 8-col group
    int j0 = gj*8;
    const float* sl = ws + OFF_SUMLO + (size_t)b*NN*NN;
    float mv[4][8], s2[4][8], s4[4][8], s8[4][8];
#pragma unroll
    for (int p=0;p<4;++p)
#pragma unroll
        for (int q=0;q<8;++q) {
            mv[p][q] = sl[(i0+p)*NN + j0+q] * INV_W;
            s2[p][q] = 0.f; s4[p][q] = 0.f; s8[p][q] = 0.f;
        }

    int gia = i0 >> 3, la = i0 & 7;   // a-fragment phys offset pieces
    for (int w = w0; w < w1; ++w) {
        __syncthreads();
        stage_window(x, ws, b, w, tid, y);
        __syncthreads();
        float dot[4][8];
#pragma unroll
        for (int p=0;p<4;++p)
#pragma unroll
            for (int q=0;q<8;++q) dot[p][q] = 0.f;
#pragma unroll 6
        for (int t = 0; t < WIN; ++t) {
            const float* row = &y[t*ROWF];
            float4 a0 = *(const float4*)&row[12*gia + la];
            float4 b0 = *(const float4*)&row[12*gj];
            float4 b1 = *(const float4*)&row[12*gj+4];
            float av[4] = {a0.x,a0.y,a0.z,a0.w};
            float bv[8] = {b0.x,b0.y,b0.z,b0.w,b1.x,b1.y,b1.z,b1.w};
#pragma unroll
            for (int p=0;p<4;++p)
#pragma unroll
                for (int q=0;q<8;++q) dot[p][q] = fmaf(av[p], bv[q], dot[p][q]);
        }
#pragma unroll
        for (int p=0;p<4;++p)
#pragma unroll
            for (int q=0;q<8;++q) {
                float c = dot[p][q] - mv[p][q];
                float p2 = c*c, p4 = p2*p2;
                s2[p][q] += p2; s4[p][q] += p4; s8[p][q] += p4*p4;
            }
    }
    float nwf = (float)(w1 - w0);
#pragma unroll
    for (int p=0;p<4;++p)
#pragma unroll
        for (int q=0;q<8;++q) {
            int ii = i0+p, jj = j0+q;
            float a2 = s2[p][q], a4 = s4[p][q], a8 = s8[p][q];
            if (ii == jj) {   // corr diag == 1 exactly every window
                float c = 1.0f - mv[p][q];
                float p2 = c*c, p4 = p2*p2, p8 = p4*p4;
                a2 = nwf*p2; a4 = nwf*p4; a8 = nwf*p8;
            }
            atomicAdd(&ws[OFF_CM2 + (size_t)b*NN*NN + ii*NN+jj], a2);
            atomicAdd(&ws[OFF_CM4 + (size_t)b*NN*NN + ii*NN+jj], a4);
            atomicAdd(&ws[OFF_CM8 + (size_t)b*NN*NN + ii*NN+jj], a8);
        }
}

// ---------------------------------------------------------------- K5: rowwise_corr per (b, d), accumulate A_sum
__global__ __launch_bounds__(256) void k5_rowcorr(float* __restrict__ ws) {
    __shared__ float Xc[NN][NN+1];
    __shared__ float rmn[NN];
    __shared__ float iden[NN];
    int b = blockIdx.x / 3, di = blockIdx.x % 3;
    const float* cm = ws + (di==0 ? OFF_CM2 : (di==1 ? OFF_CM4 : OFF_CM8)) + (size_t)b*NN*NN;
    int tid = threadIdx.x;
    for (int idx = tid; idx < NN*NN; idx += 256) {
        int n = idx >> 7, f = idx & 127;
        Xc[n][f] = cm[idx] * INV_W;
    }
    __syncthreads();
    if (tid < NN) {
        float s = 0.f;
        for (int f = 0; f < NN; ++f) s += Xc[tid][f];
        rmn[tid] = s * (1.0f/NN);
    }
    __syncthreads();
    for (int idx = tid; idx < NN*NN; idx += 256) {
        int n = idx >> 7, f = idx & 127;
        Xc[n][f] -= rmn[n];
    }
    __syncthreads();
    int n0 = (tid >> 4)*8, m0 = (tid & 15)*8;
    float acc[8][8];
#pragma unroll
    for (int k=0;k<8;++k)
#pragma unroll
        for (int l=0;l<8;++l) acc[k][l] = 0.f;
    for (int f = 0; f < NN; ++f) {
        float an[8], am[8];
#pragma unroll
        for (int k=0;k<8;++k) { an[k] = Xc[n0+k][f]; am[k] = Xc[m0+k][f]; }
#pragma unroll
        for (int k=0;k<8;++k)
#pragma unroll
            for (int l=0;l<8;++l) acc[k][l] = fmaf(an[k], am[l], acc[k][l]);
    }
    if (n0 == m0) {
#pragma unroll
        for (int k=0;k<8;++k) iden[n0+k] = 1.0f/sqrtf(fmaxf(acc[k][k], 1e-8f));
    }
    __syncthreads();
    float* As = ws + OFF_ASUM + (size_t)b*NN*NN;
#pragma unroll
    for (int k=0;k<8;++k)
#pragma unroll
        for (int l=0;l<8;++l) {
            int gi = n0+k, gj = m0+l;
            float v = acc[k][l]*iden[gi]*iden[gj];
            if (gi == gj) v = 1.0f;
            atomicAdd(&As[gi*NN+gj], v);
        }
}

// ---------------------------------------------------------------- K6: symmetrize + normalize adjacency
__global__ __launch_bounds__(256) void k6_anorm(float* __restrict__ ws) {
    __shared__ float As[NN][NN+1];
    __shared__ float dis[NN];
    int b = blockIdx.x;
    const float* Asum = ws + OFF_ASUM + (size_t)b*NN*NN;
    int tid = threadIdx.x;
    for (int idx = tid; idx < NN*NN; idx += 256) {
        int n = idx >> 7, m = idx & 127;
        As[n][m] = (Asum[n*NN+m] + Asum[m*NN+n]) * (1.0f/6.0f);  // mean-of-3 then 0.5*(A+A^T)
    }
    __syncthreads();
    if (tid < NN) {
        float d = 1.0f;                       // +I diag
        for (int m = 0; m < NN; ++m) d += As[tid][m];
        dis[tid] = sqrtf(1.0f / fmaxf(d, 1e-8f));
    }
    __syncthreads();
    float* An = ws + OFF_ANORM + (size_t)b*NN*NN;
    for (int idx = tid; idx < NN*NN; idx += 256) {
        int n = idx >> 7, m = idx & 127;
        float v = As[n][m] + (n==m ? 1.0f : 0.0f);
        An[idx] = v * dis[n] * dis[m];
    }
}

// ---------------------------------------------------------------- K7: build X (concat cm2,4,8) + layernorm
__global__ __launch_bounds__(128) void k7_ln(const float* __restrict__ gamma, const float* __restrict__ beta,
                                             float* __restrict__ ws) {
    __shared__ float red[128];
    int row = blockIdx.x;   // b*NN + n
    int tid = threadIdx.x;
    float v0 = ws[OFF_CM2 + (size_t)row*NN + tid] * INV_W;
    float v1 = ws[OFF_CM4 + (size_t)row*NN + tid] * INV_W;
    float v2 = ws[OFF_CM8 + (size_t)row*NN + tid] * INV_W;
    red[tid] = v0+v1+v2;
    __syncthreads();
    for (int o = 64; o > 0; o >>= 1) { if (tid < o) red[tid] += red[tid+o]; __syncthreads(); }
    float mean = red[0] * (1.0f/IND);
    __syncthreads();
    float d0 = v0-mean, d1 = v1-mean, d2 = v2-mean;
    red[tid] = d0*d0 + d1*d1 + d2*d2;
    __syncthreads();
    for (int o = 64; o > 0; o >>= 1) { if (tid < o) red[tid] += red[tid+o]; __syncthreads(); }
    float rstd = 1.0f / sqrtf(red[0]*(1.0f/IND) + 1e-5f);
    float* X = ws + OFF_X + (size_t)row*IND;
    X[tid]     = d0*rstd*gamma[tid]     + beta[tid];
    X[tid+128] = d1*rstd*gamma[tid+128] + beta[tid+128];
    X[tid+256] = d2*rstd*gamma[tid+256] + beta[tid+256];
}

// ---------------------------------------------------------------- K8: dense (rows x K) @ (K x 256) + bias
__global__ __launch_bounds__(256) void k8_gemm(const float* __restrict__ Wt, const float* __restrict__ bias,
                                               const float* __restrict__ in, float* __restrict__ out, int K) {
    __shared__ float Xs[8][IND];
    int r0 = blockIdx.x * 8;
    int tid = threadIdx.x;
    for (int r = 0; r < 8; ++r)
        for (int c = tid; c < K; c += 256)
            Xs[r][c] = in[(size_t)(r0+r)*K + c];
    __syncthreads();
    float acc[8];
#pragma unroll
    for (int r = 0; r < 8; ++r) acc[r] = bias[tid];
    for (int k = 0; k < K; ++k) {
        float wv = Wt[(size_t)k*DM + tid];
#pragma unroll
        for (int r = 0; r < 8; ++r) acc[r] = fmaf(Xs[r][k], wv, acc[r]);
    }
#pragma unroll
    for (int r = 0; r < 8; ++r) out[(size_t)(r0+r)*DM + tid] = acc[r];
}

// ---------------------------------------------------------------- K9: H = relu(A_norm @ Z)
__global__ __launch_bounds__(256) void k9_prop(const float* __restrict__ Anorm, const float* __restrict__ Zin,
                                               float* __restrict__ out) {
    __shared__ float Ar[8][NN];
    int bx = blockIdx.x;
    int b = bx >> 4, n0 = (bx & 15)*8;
    int tid = threadIdx.x;
    const float* A = Anorm + (size_t)b*NN*NN;
    if (tid < NN) {
#pragma unroll
        for (int r = 0; r < 8; ++r) Ar[r][tid] = A[(n0+r)*NN + tid];
    }
    __syncthreads();
    float acc[8] = {0,0,0,0,0,0,0,0};
    const float* Z = Zin + (size_t)b*NN*DM;
    for (int m = 0; m < NN; ++m) {
        float z = Z[(size_t)m*DM + tid];
#pragma unroll
        for (int r = 0; r < 8; ++r) acc[r] = fmaf(Ar[r][m], z, acc[r]);
    }
    float* O = out + (size_t)b*NN*DM;
#pragma unroll
    for (int r = 0; r < 8; ++r) O[(size_t)(n0+r)*DM + tid] = fmaxf(acc[r], 0.0f);
}

// ---------------------------------------------------------------- K12: mean-pool + sigmoid head
__global__ __launch_bounds__(256) void k12_head(const float* __restrict__ H, const float* __restrict__ Wc,
                                                const float* __restrict__ bc, float* __restrict__ outp) {
    __shared__ float red[256];
    int b = blockIdx.x, tid = threadIdx.x;
    float s = 0.f;
    for (int n = 0; n < NN; ++n) s += H[((size_t)b*NN+n)*DM + tid];
    red[tid] = s * (1.0f/NN) * Wc[tid];
    __syncthreads();
    for (int o = 128; o > 0; o >>= 1) { if (tid < o) red[tid] += red[tid+o]; __syncthreads(); }
    if (tid == 0) outp[b] = 1.0f/(1.0f + expf(-(red[0] + bc[0])));
}

// ----------------------------------------------------------------
extern "C" void kernel_launch(void* const* d_in, const int* in_sizes, int n_in,
                              void* d_out, int out_size, void* d_ws, size_t ws_size,
                              hipStream_t stream) {
    (void)in_sizes; (void)n_in; (void)out_size; (void)ws_size;
    const float* x     = (const float*)d_in[0];
    const float* gamma = (const float*)d_in[1];
    const float* beta  = (const float*)d_in[2];
    const float* W1    = (const float*)d_in[3];
    const float* b1    = (const float*)d_in[4];
    const float* W2    = (const float*)d_in[5];
    const float* b2    = (const float*)d_in[6];
    const float* Wc    = (const float*)d_in[7];
    const float* bc    = (const float*)d_in[8];
    float* ws  = (float*)d_ws;
    float* out = (float*)d_out;

    // zero the atomic accumulators (sumlo, cm2, cm4, cm8, Asum are contiguous)
    hipMemsetAsync(ws + OFF_SUMLO, 0, (size_t)(5*BB*NN*NN)*sizeof(float), stream);

    k1_stats  <<<BB*NWD,  128, 0, stream>>>(x, ws);
    k2_sumcorr<<<BB*63,   256, 0, stream>>>(x, ws);
    k4_moments<<<BB*64,   256, 0, stream>>>(x, ws);
    k5_rowcorr<<<BB*3,    256, 0, stream>>>(ws);
    k6_anorm  <<<BB,      256, 0, stream>>>(ws);
    k7_ln     <<<BB*NN,   128, 0, stream>>>(gamma, beta, ws);
    k8_gemm   <<<BB*NN/8, 256, 0, stream>>>(W1, b1, ws + OFF_X,    ws + OFF_BUFA, IND);
    k9_prop   <<<BB*16,   256, 0, stream>>>(ws + OFF_ANORM, ws + OFF_BUFA, ws + OFF_BUFB);
    k8_gemm   <<<BB*NN/8, 256, 0, stream>>>(W2, b2, ws + OFF_BUFB, ws + OFF_BUFA, DM);
    k9_prop   <<<BB*16,   256, 0, stream>>>(ws + OFF_ANORM, ws + OFF_BUFA, ws + OFF_BUFB);
    k12_head  <<<BB,      256, 0, stream>>>(ws + OFF_BUFB, Wc, bc, out);
}

// Round 3
// 571.423 us; speedup vs baseline: 2.6340x; 2.6340x over previous
//
#include <hip/hip_runtime.h>
#include <math.h>

#define BB  16
#define TT  1024
#define NN  128
#define WIN 30
#define NWD 498          // number of windows
#define DM  256          // D_MODEL
#define IND 384          // 3*N
#define NCH 8            // window chunks in k24 (64 windows each)

#define INV_W (1.0f/498.0f)

// swizzled LDS row: 16 groups of 8 floats, each group padded to 12 floats
// phys(c) = (c>>3)*12 + (c&7); row stride 192 floats (768 B)
#define ROWF 192

#define SARR (BB*NN*NN)  // one moment-sum array

// workspace offsets in floats
#define OFF_MU    0
#define OFF_RSTD  (OFF_MU   + BB*NWD*NN)
#define OFF_S     (OFF_RSTD + BB*NWD*NN)   // S1..S8, 8 arrays of SARR
#define OFF_CM2   (OFF_S    + 8*SARR)
#define OFF_CM4   (OFF_CM2  + SARR)
#define OFF_CM8   (OFF_CM4  + SARR)
#define OFF_ASUM  (OFF_CM8  + SARR)
#define OFF_ANORM (OFF_ASUM + SARR)
#define OFF_X     (OFF_ANORM + SARR)
#define OFF_BUFA  (OFF_X    + BB*NN*IND)
#define OFF_BUFB  (OFF_BUFA + BB*NN*DM)

// ---------------------------------------------------------------- K1: per-window channel stats (single pass)
__global__ __launch_bounds__(128) void k1_stats(const float* __restrict__ x, float* __restrict__ ws) {
    int bw = blockIdx.x;            // b*NWD + w
    int b = bw / NWD, w = bw - b*NWD;
    int n = threadIdx.x;
    int s = w * 2;
    const float* xp = x + ((size_t)(b*TT + s))*NN + n;
    float sum = 0.f, sq = 0.f;
#pragma unroll
    for (int t = 0; t < WIN; ++t) { float v = xp[t*NN]; sum += v; sq = fmaf(v, v, sq); }
    float mean = sum * (1.0f/30.0f);
    float ss = sq - 30.0f*mean*mean;
    float var = fmaxf(ss * (1.0f/29.0f), 1e-8f);
    float r = 1.0f / sqrtf(var);
    ws[OFF_MU   + bw*NN + n] = mean;
    // fold 1/sqrt(29) so corr(i,j) = sum_t y_i y_j directly
    ws[OFF_RSTD + bw*NN + n] = r * 0.185695338f;
}

// stage one normalized window (30 x 128) into swizzled LDS; blockDim must be 256
__device__ __forceinline__ void stage_window(const float* __restrict__ x, const float* __restrict__ ws,
                                             int b, int w, int tid, float* __restrict__ y) {
    int s = w * 2;
    const float4* xr  = (const float4*)(x + (size_t)(b*TT + s)*NN);
    const float4* mu4 = (const float4*)(ws + OFF_MU   + (size_t)(b*NWD + w)*NN);
    const float4* rs4 = (const float4*)(ws + OFF_RSTD + (size_t)(b*NWD + w)*NN);
    for (int idx = tid; idx < WIN*32; idx += 256) {
        int t = idx >> 5, c4 = idx & 31;
        float4 xv = xr[t*32 + c4];
        float4 m  = mu4[c4];
        float4 rv = rs4[c4];
        float4 o;
        o.x = (xv.x - m.x) * rv.x;
        o.y = (xv.y - m.y) * rv.y;
        o.z = (xv.z - m.z) * rv.z;
        o.w = (xv.w - m.w) * rv.w;
        int phys = t*ROWF + (c4 >> 1)*12 + (c4 & 1)*4;
        *(float4*)&y[phys] = o;
    }
}

// ---------------------------------------------------------------- K24: single pass, power sums S1..S8 of corr
// grid = BB * NCH * 4 quadrants; 4x4 thread tiles over a 64x64 quadrant
__global__ __launch_bounds__(256, 2) void k24_powsums(const float* __restrict__ x, float* __restrict__ ws) {
    __shared__ __align__(16) float y[WIN*ROWF];
    int bx = blockIdx.x;
    int b   = bx >> 5;               // / (NCH*4)
    int rem = bx & 31;
    int ch = rem >> 2, quad = rem & 3;
    int w0 = ch*64, w1 = min(NWD, w0 + 64);
    int tid = threadIdx.x;
    int i0 = (quad >> 1)*64 + (tid >> 4)*4;
    int j0 = (quad &  1)*64 + (tid & 15)*4;
    // phys offsets of the a/b float4 fragments (aligned: i0%8 in {0,4})
    int pa = (i0 >> 3)*12 + (i0 & 7);
    int pb = (j0 >> 3)*12 + (j0 & 7);

    float S1[4][4], S2[4][4], S3[4][4], S4[4][4], S5[4][4], S6[4][4], S7[4][4], S8[4][4];
#pragma unroll
    for (int p=0;p<4;++p)
#pragma unroll
        for (int q=0;q<4;++q) {
            S1[p][q]=0.f;S2[p][q]=0.f;S3[p][q]=0.f;S4[p][q]=0.f;
            S5[p][q]=0.f;S6[p][q]=0.f;S7[p][q]=0.f;S8[p][q]=0.f;
        }

    for (int w = w0; w < w1; ++w) {
        __syncthreads();
        stage_window(x, ws, b, w, tid, y);
        __syncthreads();
        float dot[4][4];
#pragma unroll
        for (int p=0;p<4;++p)
#pragma unroll
            for (int q=0;q<4;++q) dot[p][q] = 0.f;
#pragma unroll 6
        for (int t = 0; t < WIN; ++t) {
            const float* row = &y[t*ROWF];
            float4 a0 = *(const float4*)&row[pa];
            float4 b0 = *(const float4*)&row[pb];
            float av[4] = {a0.x,a0.y,a0.z,a0.w};
            float bv[4] = {b0.x,b0.y,b0.z,b0.w};
#pragma unroll
            for (int p=0;p<4;++p)
#pragma unroll
                for (int q=0;q<4;++q) dot[p][q] = fmaf(av[p], bv[q], dot[p][q]);
        }
#pragma unroll
        for (int p=0;p<4;++p)
#pragma unroll
            for (int q=0;q<4;++q) {
                float c  = dot[p][q];
                float c2 = c*c;
                float c3 = c2*c;
                float c4 = c2*c2;
                S1[p][q] += c;
                S2[p][q] += c2;
                S3[p][q] += c3;
                S4[p][q] += c4;
                S5[p][q] = fmaf(c4, c,  S5[p][q]);
                S6[p][q] = fmaf(c3, c3, S6[p][q]);
                S7[p][q] = fmaf(c3, c4, S7[p][q]);
                S8[p][q] = fmaf(c4, c4, S8[p][q]);
            }
    }
    float* base = ws + OFF_S + (size_t)b*NN*NN;
#pragma unroll
    for (int p=0;p<4;++p)
#pragma unroll
        for (int q=0;q<4;++q) {
            size_t o = (size_t)(i0+p)*NN + (j0+q);
            atomicAdd(base + 0*SARR + o, S1[p][q]);
            atomicAdd(base + 1*SARR + o, S2[p][q]);
            atomicAdd(base + 2*SARR + o, S3[p][q]);
            atomicAdd(base + 3*SARR + o, S4[p][q]);
            atomicAdd(base + 4*SARR + o, S5[p][q]);
            atomicAdd(base + 5*SARR + o, S6[p][q]);
            atomicAdd(base + 6*SARR + o, S7[p][q]);
            atomicAdd(base + 7*SARR + o, S8[p][q]);
        }
}

// ---------------------------------------------------------------- Kcomb: reconstruct centered moments from S1..S8
__global__ __launch_bounds__(256) void kcomb(float* __restrict__ ws) {
    int idx = blockIdx.x*256 + threadIdx.x;   // over BB*NN*NN
    int i = (idx >> 7) & 127, j = idx & 127;
    float cm2, cm4, cm8;
    if (i == j) {
        cm2 = 0.f; cm4 = 0.f; cm8 = 0.f;      // corr diag == 1 every window -> centered == 0
    } else {
        const float* S = ws + OFF_S + idx;
        float e1 = S[0*SARR]*INV_W, e2 = S[1*SARR]*INV_W, e3 = S[2*SARR]*INV_W, e4 = S[3*SARR]*INV_W;
        float e5 = S[4*SARR]*INV_W, e6 = S[5*SARR]*INV_W, e7 = S[6*SARR]*INV_W, e8 = S[7*SARR]*INV_W;
        float m  = e1;
        float m2 = m*m, m3 = m2*m, m4 = m2*m2, m5 = m4*m, m6 = m3*m3, m8 = m4*m4;
        cm2 = e2 - m2;
        cm4 = e4 - 4.f*m*e3 + 6.f*m2*e2 - 3.f*m4;
        cm8 = e8 - 8.f*m*e7 + 28.f*m2*e6 - 56.f*m3*e5 + 70.f*m4*e4
                 - 56.f*m5*e3 + 28.f*m6*e2 - 7.f*m8;
    }
    ws[OFF_CM2 + idx] = cm2;
    ws[OFF_CM4 + idx] = cm4;
    ws[OFF_CM8 + idx] = cm8;
}

// ---------------------------------------------------------------- K5: rowwise_corr per (b, d), accumulate A_sum
__global__ __launch_bounds__(256) void k5_rowcorr(float* __restrict__ ws) {
    __shared__ float Xc[NN][NN+1];
    __shared__ float rmn[NN];
    __shared__ float iden[NN];
    int b = blockIdx.x / 3, di = blockIdx.x % 3;
    const float* cm = ws + (di==0 ? OFF_CM2 : (di==1 ? OFF_CM4 : OFF_CM8)) + (size_t)b*NN*NN;
    int tid = threadIdx.x;
    for (int idx = tid; idx < NN*NN; idx += 256) {
        int n = idx >> 7, f = idx & 127;
        Xc[n][f] = cm[idx];
    }
    __syncthreads();
    if (tid < NN) {
        float s = 0.f;
        for (int f = 0; f < NN; ++f) s += Xc[tid][f];
        rmn[tid] = s * (1.0f/NN);
    }
    __syncthreads();
    for (int idx = tid; idx < NN*NN; idx += 256) {
        int n = idx >> 7, f = idx & 127;
        Xc[n][f] -= rmn[n];
    }
    __syncthreads();
    int n0 = (tid >> 4)*8, m0 = (tid & 15)*8;
    float acc[8][8];
#pragma unroll
    for (int k=0;k<8;++k)
#pragma unroll
        for (int l=0;l<8;++l) acc[k][l] = 0.f;
    for (int f = 0; f < NN; ++f) {
        float an[8], am[8];
#pragma unroll
        for (int k=0;k<8;++k) { an[k] = Xc[n0+k][f]; am[k] = Xc[m0+k][f]; }
#pragma unroll
        for (int k=0;k<8;++k)
#pragma unroll
            for (int l=0;l<8;++l) acc[k][l] = fmaf(an[k], am[l], acc[k][l]);
    }
    if (n0 == m0) {
#pragma unroll
        for (int k=0;k<8;++k) iden[n0+k] = 1.0f/sqrtf(fmaxf(acc[k][k], 1e-8f));
    }
    __syncthreads();
    float* As = ws + OFF_ASUM + (size_t)b*NN*NN;
#pragma unroll
    for (int k=0;k<8;++k)
#pragma unroll
        for (int l=0;l<8;++l) {
            int gi = n0+k, gj = m0+l;
            float v = acc[k][l]*iden[gi]*iden[gj];
            if (gi == gj) v = 1.0f;
            atomicAdd(&As[gi*NN+gj], v);
        }
}

// ---------------------------------------------------------------- K6: symmetrize + normalize adjacency
__global__ __launch_bounds__(256) void k6_anorm(float* __restrict__ ws) {
    __shared__ float As[NN][NN+1];
    __shared__ float dis[NN];
    int b = blockIdx.x;
    const float* Asum = ws + OFF_ASUM + (size_t)b*NN*NN;
    int tid = threadIdx.x;
    for (int idx = tid; idx < NN*NN; idx += 256) {
        int n = idx >> 7, m = idx & 127;
        As[n][m] = (Asum[n*NN+m] + Asum[m*NN+n]) * (1.0f/6.0f);  // mean-of-3 then 0.5*(A+A^T)
    }
    __syncthreads();
    if (tid < NN) {
        float d = 1.0f;                       // +I diag
        for (int m = 0; m < NN; ++m) d += As[tid][m];
        dis[tid] = sqrtf(1.0f / fmaxf(d, 1e-8f));
    }
    __syncthreads();
    float* An = ws + OFF_ANORM + (size_t)b*NN*NN;
    for (int idx = tid; idx < NN*NN; idx += 256) {
        int n = idx >> 7, m = idx & 127;
        float v = As[n][m] + (n==m ? 1.0f : 0.0f);
        An[idx] = v * dis[n] * dis[m];
    }
}

// ---------------------------------------------------------------- K7: build X (concat cm2,4,8) + layernorm
__global__ __launch_bounds__(128) void k7_ln(const float* __restrict__ gamma, const float* __restrict__ beta,
                                             float* __restrict__ ws) {
    __shared__ float red[128];
    int row = blockIdx.x;   // b*NN + n
    int tid = threadIdx.x;
    float v0 = ws[OFF_CM2 + (size_t)row*NN + tid];
    float v1 = ws[OFF_CM4 + (size_t)row*NN + tid];
    float v2 = ws[OFF_CM8 + (size_t)row*NN + tid];
    red[tid] = v0+v1+v2;
    __syncthreads();
    for (int o = 64; o > 0; o >>= 1) { if (tid < o) red[tid] += red[tid+o]; __syncthreads(); }
    float mean = red[0] * (1.0f/IND);
    __syncthreads();
    float d0 = v0-mean, d1 = v1-mean, d2 = v2-mean;
    red[tid] = d0*d0 + d1*d1 + d2*d2;
    __syncthreads();
    for (int o = 64; o > 0; o >>= 1) { if (tid < o) red[tid] += red[tid+o]; __syncthreads(); }
    float rstd = 1.0f / sqrtf(red[0]*(1.0f/IND) + 1e-5f);
    float* X = ws + OFF_X + (size_t)row*IND;
    X[tid]     = d0*rstd*gamma[tid]     + beta[tid];
    X[tid+128] = d1*rstd*gamma[tid+128] + beta[tid+128];
    X[tid+256] = d2*rstd*gamma[tid+256] + beta[tid+256];
}

// ---------------------------------------------------------------- K8: dense (rows x K) @ (K x 256) + bias
__global__ __launch_bounds__(256) void k8_gemm(const float* __restrict__ Wt, const float* __restrict__ bias,
                                               const float* __restrict__ in, float* __restrict__ out, int K) {
    __shared__ float Xs[8][IND];
    int r0 = blockIdx.x * 8;
    int tid = threadIdx.x;
    for (int r = 0; r < 8; ++r)
        for (int c = tid; c < K; c += 256)
            Xs[r][c] = in[(size_t)(r0+r)*K + c];
    __syncthreads();
    float acc[8];
#pragma unroll
    for (int r = 0; r < 8; ++r) acc[r] = bias[tid];
    for (int k = 0; k < K; ++k) {
        float wv = Wt[(size_t)k*DM + tid];
#pragma unroll
        for (int r = 0; r < 8; ++r) acc[r] = fmaf(Xs[r][k], wv, acc[r]);
    }
#pragma unroll
    for (int r = 0; r < 8; ++r) out[(size_t)(r0+r)*DM + tid] = acc[r];
}

// ---------------------------------------------------------------- K9: H = relu(A_norm @ Z)
__global__ __launch_bounds__(256) void k9_prop(const float* __restrict__ Anorm, const float* __restrict__ Zin,
                                               float* __restrict__ out) {
    __shared__ float Ar[8][NN];
    int bx = blockIdx.x;
    int b = bx >> 4, n0 = (bx & 15)*8;
    int tid = threadIdx.x;
    const float* A = Anorm + (size_t)b*NN*NN;
    if (tid < NN) {
#pragma unroll
        for (int r = 0; r < 8; ++r) Ar[r][tid] = A[(n0+r)*NN + tid];
    }
    __syncthreads();
    float acc[8] = {0,0,0,0,0,0,0,0};
    const float* Z = Zin + (size_t)b*NN*DM;
    for (int m = 0; m < NN; ++m) {
        float z = Z[(size_t)m*DM + tid];
#pragma unroll
        for (int r = 0; r < 8; ++r) acc[r] = fmaf(Ar[r][m], z, acc[r]);
    }
    float* O = out + (size_t)b*NN*DM;
#pragma unroll
    for (int r = 0; r < 8; ++r) O[(size_t)(n0+r)*DM + tid] = fmaxf(acc[r], 0.0f);
}

// ---------------------------------------------------------------- K12: mean-pool + sigmoid head
__global__ __launch_bounds__(256) void k12_head(const float* __restrict__ H, const float* __restrict__ Wc,
                                                const float* __restrict__ bc, float* __restrict__ outp) {
    __shared__ float red[256];
    int b = blockIdx.x, tid = threadIdx.x;
    float s = 0.f;
    for (int n = 0; n < NN; ++n) s += H[((size_t)b*NN+n)*DM + tid];
    red[tid] = s * (1.0f/NN) * Wc[tid];
    __syncthreads();
    for (int o = 128; o > 0; o >>= 1) { if (tid < o) red[tid] += red[tid+o]; __syncthreads(); }
    if (tid == 0) outp[b] = 1.0f/(1.0f + expf(-(red[0] + bc[0])));
}

// ----------------------------------------------------------------
extern "C" void kernel_launch(void* const* d_in, const int* in_sizes, int n_in,
                              void* d_out, int out_size, void* d_ws, size_t ws_size,
                              hipStream_t stream) {
    (void)in_sizes; (void)n_in; (void)out_size; (void)ws_size;
    const float* x     = (const float*)d_in[0];
    const float* gamma = (const float*)d_in[1];
    const float* beta  = (const float*)d_in[2];
    const float* W1    = (const float*)d_in[3];
    const float* b1    = (const float*)d_in[4];
    const float* W2    = (const float*)d_in[5];
    const float* b2    = (const float*)d_in[6];
    const float* Wc    = (const float*)d_in[7];
    const float* bc    = (const float*)d_in[8];
    float* ws  = (float*)d_ws;
    float* out = (float*)d_out;

    // zero the atomic accumulators: S1..S8 and Asum
    hipMemsetAsync(ws + OFF_S,    0, (size_t)(8*SARR)*sizeof(float), stream);
    hipMemsetAsync(ws + OFF_ASUM, 0, (size_t)SARR*sizeof(float), stream);

    k1_stats   <<<BB*NWD,      128, 0, stream>>>(x, ws);
    k24_powsums<<<BB*NCH*4,    256, 0, stream>>>(x, ws);
    kcomb      <<<BB*NN*NN/256,256, 0, stream>>>(ws);
    k5_rowcorr <<<BB*3,        256, 0, stream>>>(ws);
    k6_anorm   <<<BB,          256, 0, stream>>>(ws);
    k7_ln      <<<BB*NN,       128, 0, stream>>>(gamma, beta, ws);
    k8_gemm    <<<BB*NN/8,     256, 0, stream>>>(W1, b1, ws + OFF_X,    ws + OFF_BUFA, IND);
    k9_prop    <<<BB*16,       256, 0, stream>>>(ws + OFF_ANORM, ws + OFF_BUFA, ws + OFF_BUFB);
    k8_gemm    <<<BB*NN/8,     256, 0, stream>>>(W2, b2, ws + OFF_BUFB, ws + OFF_BUFA, DM);
    k9_prop    <<<BB*16,       256, 0, stream>>>(ws + OFF_ANORM, ws + OFF_BUFA, ws + OFF_BUFB);
    k12_head   <<<BB,          256, 0, stream>>>(ws + OFF_BUFB, Wc, bc, out);
}

// Round 4
// 543.176 us; speedup vs baseline: 2.7710x; 1.0520x over previous
//
#include <hip/hip_runtime.h>
#include <math.h>

#define BB  16
#define TT  1024
#define NN  128
#define WIN 30
#define NWD 498          // number of windows
#define DM  256          // D_MODEL
#define IND 384          // 3*N
#define NCH 8            // window chunks in k24 (64 windows each)

#define INV_W (1.0f/498.0f)

// swizzled LDS row: 16 groups of 8 floats, each group padded to 12 floats
// phys(c) = (c>>3)*12 + (c&7); row stride 192 floats (768 B)
#define ROWF 192

#define SARR (BB*NN*NN)  // one moment-sum array

// workspace offsets in floats
#define OFF_MU    0
#define OFF_RSTD  (OFF_MU   + BB*NWD*NN)
#define OFF_S     (OFF_RSTD + BB*NWD*NN)   // S1..S8, 8 arrays of SARR
#define OFF_CM2   (OFF_S    + 8*SARR)
#define OFF_CM4   (OFF_CM2  + SARR)
#define OFF_CM8   (OFF_CM4  + SARR)
#define OFF_ASUM  (OFF_CM8  + SARR)
#define OFF_ANORM (OFF_ASUM + SARR)
#define OFF_X     (OFF_ANORM + SARR)
#define OFF_BUFA  (OFF_X    + BB*NN*IND)
#define OFF_BUFB  (OFF_BUFA + BB*NN*DM)

// ---------------------------------------------------------------- K1: per-window channel stats (single pass)
__global__ __launch_bounds__(128) void k1_stats(const float* __restrict__ x, float* __restrict__ ws) {
    int bw = blockIdx.x;            // b*NWD + w
    int b = bw / NWD, w = bw - b*NWD;
    int n = threadIdx.x;
    int s = w * 2;
    const float* xp = x + ((size_t)(b*TT + s))*NN + n;
    float sum = 0.f, sq = 0.f;
#pragma unroll
    for (int t = 0; t < WIN; ++t) { float v = xp[t*NN]; sum += v; sq = fmaf(v, v, sq); }
    float mean = sum * (1.0f/30.0f);
    float ss = sq - 30.0f*mean*mean;
    float var = fmaxf(ss * (1.0f/29.0f), 1e-8f);
    float r = 1.0f / sqrtf(var);
    ws[OFF_MU   + bw*NN + n] = mean;
    // fold 1/sqrt(29) so corr(i,j) = sum_t y_i y_j directly
    ws[OFF_RSTD + bw*NN + n] = r * 0.185695338f;
}

// stage one normalized window (30 x 128) into swizzled LDS; blockDim must be 256
__device__ __forceinline__ void stage_window(const float* __restrict__ x, const float* __restrict__ ws,
                                             int b, int w, int tid, float* __restrict__ y) {
    int s = w * 2;
    const float4* xr  = (const float4*)(x + (size_t)(b*TT + s)*NN);
    const float4* mu4 = (const float4*)(ws + OFF_MU   + (size_t)(b*NWD + w)*NN);
    const float4* rs4 = (const float4*)(ws + OFF_RSTD + (size_t)(b*NWD + w)*NN);
    for (int idx = tid; idx < WIN*32; idx += 256) {
        int t = idx >> 5, c4 = idx & 31;
        float4 xv = xr[t*32 + c4];
        float4 m  = mu4[c4];
        float4 rv = rs4[c4];
        float4 o;
        o.x = (xv.x - m.x) * rv.x;
        o.y = (xv.y - m.y) * rv.y;
        o.z = (xv.z - m.z) * rv.z;
        o.w = (xv.w - m.w) * rv.w;
        int phys = t*ROWF + (c4 >> 1)*12 + (c4 & 1)*4;
        *(float4*)&y[phys] = o;
    }
}

// ---------------------------------------------------------------- K24: single pass, power sums S1..S8 of corr
// grid = BB * NCH * 4 quadrants; 4x4 thread tiles over a 64x64 quadrant
// amdgpu_waves_per_eu(2,2): pin backend occupancy target to 2 waves/EU so the
// ~190-float live set (128 S + 16 dot + staging/addr) gets real VGPRs, no spill.
__global__ __launch_bounds__(256) __attribute__((amdgpu_waves_per_eu(2, 2)))
void k24_powsums(const float* __restrict__ x, float* __restrict__ ws) {
    __shared__ __align__(16) float y0[WIN*ROWF];
    __shared__ __align__(16) float y1[WIN*ROWF];
    int bx = blockIdx.x;
    int b   = bx >> 5;               // / (NCH*4)
    int rem = bx & 31;
    int ch = rem >> 2, quad = rem & 3;
    int w0 = ch*64, w1 = min(NWD, w0 + 64);
    int tid = threadIdx.x;
    int i0 = (quad >> 1)*64 + (tid >> 4)*4;
    int j0 = (quad &  1)*64 + (tid & 15)*4;
    // phys offsets of the a/b float4 fragments (aligned: i0%8 in {0,4})
    int pa = (i0 >> 3)*12 + (i0 & 7);
    int pb = (j0 >> 3)*12 + (j0 & 7);

    float S1[4][4], S2[4][4], S3[4][4], S4[4][4], S5[4][4], S6[4][4], S7[4][4], S8[4][4];
#pragma unroll
    for (int p=0;p<4;++p)
#pragma unroll
        for (int q=0;q<4;++q) {
            S1[p][q]=0.f;S2[p][q]=0.f;S3[p][q]=0.f;S4[p][q]=0.f;
            S5[p][q]=0.f;S6[p][q]=0.f;S7[p][q]=0.f;S8[p][q]=0.f;
        }

    stage_window(x, ws, b, w0, tid, y0);
    for (int w = w0; w < w1; ++w) {
        float* ycur = ((w - w0) & 1) ? y1 : y0;
        float* ynxt = ((w - w0) & 1) ? y0 : y1;
        __syncthreads();                       // staging of ycur done; prior compute on ynxt done
        if (w + 1 < w1) stage_window(x, ws, b, w + 1, tid, ynxt);
        float dot[4][4];
#pragma unroll
        for (int p=0;p<4;++p)
#pragma unroll
            for (int q=0;q<4;++q) dot[p][q] = 0.f;
#pragma unroll 6
        for (int t = 0; t < WIN; ++t) {
            const float* row = &ycur[t*ROWF];
            float4 a0 = *(const float4*)&row[pa];
            float4 b0 = *(const float4*)&row[pb];
            float av[4] = {a0.x,a0.y,a0.z,a0.w};
            float bv[4] = {b0.x,b0.y,b0.z,b0.w};
#pragma unroll
            for (int p=0;p<4;++p)
#pragma unroll
                for (int q=0;q<4;++q) dot[p][q] = fmaf(av[p], bv[q], dot[p][q]);
        }
#pragma unroll
        for (int p=0;p<4;++p)
#pragma unroll
            for (int q=0;q<4;++q) {
                float c  = dot[p][q];
                float c2 = c*c;
                float c3 = c2*c;
                float c4 = c2*c2;
                S1[p][q] += c;
                S2[p][q] += c2;
                S3[p][q] += c3;
                S4[p][q] += c4;
                S5[p][q] = fmaf(c4, c,  S5[p][q]);
                S6[p][q] = fmaf(c3, c3, S6[p][q]);
                S7[p][q] = fmaf(c3, c4, S7[p][q]);
                S8[p][q] = fmaf(c4, c4, S8[p][q]);
            }
    }
    float* base = ws + OFF_S + (size_t)b*NN*NN;
#pragma unroll
    for (int p=0;p<4;++p)
#pragma unroll
        for (int q=0;q<4;++q) {
            size_t o = (size_t)(i0+p)*NN + (j0+q);
            atomicAdd(base + 0*SARR + o, S1[p][q]);
            atomicAdd(base + 1*SARR + o, S2[p][q]);
            atomicAdd(base + 2*SARR + o, S3[p][q]);
            atomicAdd(base + 3*SARR + o, S4[p][q]);
            atomicAdd(base + 4*SARR + o, S5[p][q]);
            atomicAdd(base + 5*SARR + o, S6[p][q]);
            atomicAdd(base + 6*SARR + o, S7[p][q]);
            atomicAdd(base + 7*SARR + o, S8[p][q]);
        }
}

// ---------------------------------------------------------------- Kcomb: reconstruct centered moments from S1..S8
__global__ __launch_bounds__(256) void kcomb(float* __restrict__ ws) {
    int idx = blockIdx.x*256 + threadIdx.x;   // over BB*NN*NN
    int i = (idx >> 7) & 127, j = idx & 127;
    float cm2, cm4, cm8;
    if (i == j) {
        cm2 = 0.f; cm4 = 0.f; cm8 = 0.f;      // corr diag == 1 every window -> centered == 0
    } else {
        const float* S = ws + OFF_S + idx;
        float e1 = S[0*SARR]*INV_W, e2 = S[1*SARR]*INV_W, e3 = S[2*SARR]*INV_W, e4 = S[3*SARR]*INV_W;
        float e5 = S[4*SARR]*INV_W, e6 = S[5*SARR]*INV_W, e7 = S[6*SARR]*INV_W, e8 = S[7*SARR]*INV_W;
        float m  = e1;
        float m2 = m*m, m3 = m2*m, m4 = m2*m2, m5 = m4*m, m6 = m3*m3, m8 = m4*m4;
        cm2 = e2 - m2;
        cm4 = e4 - 4.f*m*e3 + 6.f*m2*e2 - 3.f*m4;
        cm8 = e8 - 8.f*m*e7 + 28.f*m2*e6 - 56.f*m3*e5 + 70.f*m4*e4
                 - 56.f*m5*e3 + 28.f*m6*e2 - 7.f*m8;
    }
    ws[OFF_CM2 + idx] = cm2;
    ws[OFF_CM4 + idx] = cm4;
    ws[OFF_CM8 + idx] = cm8;
}

// ---------------------------------------------------------------- K5: rowwise_corr per (b, d), accumulate A_sum
__global__ __launch_bounds__(256) __attribute__((amdgpu_waves_per_eu(1, 2)))
void k5_rowcorr(float* __restrict__ ws) {
    __shared__ float Xc[NN][NN+1];
    __shared__ float rmn[NN];
    __shared__ float iden[NN];
    int b = blockIdx.x / 3, di = blockIdx.x % 3;
    const float* cm = ws + (di==0 ? OFF_CM2 : (di==1 ? OFF_CM4 : OFF_CM8)) + (size_t)b*NN*NN;
    int tid = threadIdx.x;
    for (int idx = tid; idx < NN*NN; idx += 256) {
        int n = idx >> 7, f = idx & 127;
        Xc[n][f] = cm[idx];
    }
    __syncthreads();
    if (tid < NN) {
        float s = 0.f;
        for (int f = 0; f < NN; ++f) s += Xc[tid][f];
        rmn[tid] = s * (1.0f/NN);
    }
    __syncthreads();
    for (int idx = tid; idx < NN*NN; idx += 256) {
        int n = idx >> 7, f = idx & 127;
        Xc[n][f] -= rmn[n];
    }
    __syncthreads();
    int n0 = (tid >> 4)*8, m0 = (tid & 15)*8;
    float acc[8][8];
#pragma unroll
    for (int k=0;k<8;++k)
#pragma unroll
        for (int l=0;l<8;++l) acc[k][l] = 0.f;
    for (int f = 0; f < NN; ++f) {
        float an[8], am[8];
#pragma unroll
        for (int k=0;k<8;++k) { an[k] = Xc[n0+k][f]; am[k] = Xc[m0+k][f]; }
#pragma unroll
        for (int k=0;k<8;++k)
#pragma unroll
            for (int l=0;l<8;++l) acc[k][l] = fmaf(an[k], am[l], acc[k][l]);
    }
    if (n0 == m0) {
#pragma unroll
        for (int k=0;k<8;++k) iden[n0+k] = 1.0f/sqrtf(fmaxf(acc[k][k], 1e-8f));
    }
    __syncthreads();
    float* As = ws + OFF_ASUM + (size_t)b*NN*NN;
#pragma unroll
    for (int k=0;k<8;++k)
#pragma unroll
        for (int l=0;l<8;++l) {
            int gi = n0+k, gj = m0+l;
            float v = acc[k][l]*iden[gi]*iden[gj];
            if (gi == gj) v = 1.0f;
            atomicAdd(&As[gi*NN+gj], v);
        }
}

// ---------------------------------------------------------------- K6: symmetrize + normalize adjacency
__global__ __launch_bounds__(256) void k6_anorm(float* __restrict__ ws) {
    __shared__ float As[NN][NN+1];
    __shared__ float dis[NN];
    int b = blockIdx.x;
    const float* Asum = ws + OFF_ASUM + (size_t)b*NN*NN;
    int tid = threadIdx.x;
    for (int idx = tid; idx < NN*NN; idx += 256) {
        int n = idx >> 7, m = idx & 127;
        As[n][m] = (Asum[n*NN+m] + Asum[m*NN+n]) * (1.0f/6.0f);  // mean-of-3 then 0.5*(A+A^T)
    }
    __syncthreads();
    if (tid < NN) {
        float d = 1.0f;                       // +I diag
        for (int m = 0; m < NN; ++m) d += As[tid][m];
        dis[tid] = sqrtf(1.0f / fmaxf(d, 1e-8f));
    }
    __syncthreads();
    float* An = ws + OFF_ANORM + (size_t)b*NN*NN;
    for (int idx = tid; idx < NN*NN; idx += 256) {
        int n = idx >> 7, m = idx & 127;
        float v = As[n][m] + (n==m ? 1.0f : 0.0f);
        An[idx] = v * dis[n] * dis[m];
    }
}

// ---------------------------------------------------------------- K7: build X (concat cm2,4,8) + layernorm
__global__ __launch_bounds__(128) void k7_ln(const float* __restrict__ gamma, const float* __restrict__ beta,
                                             float* __restrict__ ws) {
    __shared__ float red[128];
    int row = blockIdx.x;   // b*NN + n
    int tid = threadIdx.x;
    float v0 = ws[OFF_CM2 + (size_t)row*NN + tid];
    float v1 = ws[OFF_CM4 + (size_t)row*NN + tid];
    float v2 = ws[OFF_CM8 + (size_t)row*NN + tid];
    red[tid] = v0+v1+v2;
    __syncthreads();
    for (int o = 64; o > 0; o >>= 1) { if (tid < o) red[tid] += red[tid+o]; __syncthreads(); }
    float mean = red[0] * (1.0f/IND);
    __syncthreads();
    float d0 = v0-mean, d1 = v1-mean, d2 = v2-mean;
    red[tid] = d0*d0 + d1*d1 + d2*d2;
    __syncthreads();
    for (int o = 64; o > 0; o >>= 1) { if (tid < o) red[tid] += red[tid+o]; __syncthreads(); }
    float rstd = 1.0f / sqrtf(red[0]*(1.0f/IND) + 1e-5f);
    float* X = ws + OFF_X + (size_t)row*IND;
    X[tid]     = d0*rstd*gamma[tid]     + beta[tid];
    X[tid+128] = d1*rstd*gamma[tid+128] + beta[tid+128];
    X[tid+256] = d2*rstd*gamma[tid+256] + beta[tid+256];
}

// ---------------------------------------------------------------- K8: dense (rows x K) @ (K x 256) + bias
__global__ __launch_bounds__(256) void k8_gemm(const float* __restrict__ Wt, const float* __restrict__ bias,
                                               const float* __restrict__ in, float* __restrict__ out, int K) {
    __shared__ float Xs[8][IND];
    int r0 = blockIdx.x * 8;
    int tid = threadIdx.x;
    for (int r = 0; r < 8; ++r)
        for (int c = tid; c < K; c += 256)
            Xs[r][c] = in[(size_t)(r0+r)*K + c];
    __syncthreads();
    float acc[8];
#pragma unroll
    for (int r = 0; r < 8; ++r) acc[r] = bias[tid];
    for (int k = 0; k < K; ++k) {
        float wv = Wt[(size_t)k*DM + tid];
#pragma unroll
        for (int r = 0; r < 8; ++r) acc[r] = fmaf(Xs[r][k], wv, acc[r]);
    }
#pragma unroll
    for (int r = 0; r < 8; ++r) out[(size_t)(r0+r)*DM + tid] = acc[r];
}

// ---------------------------------------------------------------- K9: H = relu(A_norm @ Z)
__global__ __launch_bounds__(256) void k9_prop(const float* __restrict__ Anorm, const float* __restrict__ Zin,
                                               float* __restrict__ out) {
    __shared__ float Ar[8][NN];
    int bx = blockIdx.x;
    int b = bx >> 4, n0 = (bx & 15)*8;
    int tid = threadIdx.x;
    const float* A = Anorm + (size_t)b*NN*NN;
    if (tid < NN) {
#pragma unroll
        for (int r = 0; r < 8; ++r) Ar[r][tid] = A[(n0+r)*NN + tid];
    }
    __syncthreads();
    float acc[8] = {0,0,0,0,0,0,0,0};
    const float* Z = Zin + (size_t)b*NN*DM;
    for (int m = 0; m < NN; ++m) {
        float z = Z[(size_t)m*DM + tid];
#pragma unroll
        for (int r = 0; r < 8; ++r) acc[r] = fmaf(Ar[r][m], z, acc[r]);
    }
    float* O = out + (size_t)b*NN*DM;
#pragma unroll
    for (int r = 0; r < 8; ++r) O[(size_t)(n0+r)*DM + tid] = fmaxf(acc[r], 0.0f);
}

// ---------------------------------------------------------------- K12: mean-pool + sigmoid head
__global__ __launch_bounds__(256) void k12_head(const float* __restrict__ H, const float* __restrict__ Wc,
                                                const float* __restrict__ bc, float* __restrict__ outp) {
    __shared__ float red[256];
    int b = blockIdx.x, tid = threadIdx.x;
    float s = 0.f;
    for (int n = 0; n < NN; ++n) s += H[((size_t)b*NN+n)*DM + tid];
    red[tid] = s * (1.0f/NN) * Wc[tid];
    __syncthreads();
    for (int o = 128; o > 0; o >>= 1) { if (tid < o) red[tid] += red[tid+o]; __syncthreads(); }
    if (tid == 0) outp[b] = 1.0f/(1.0f + expf(-(red[0] + bc[0])));
}

// ----------------------------------------------------------------
extern "C" void kernel_launch(void* const* d_in, const int* in_sizes, int n_in,
                              void* d_out, int out_size, void* d_ws, size_t ws_size,
                              hipStream_t stream) {
    (void)in_sizes; (void)n_in; (void)out_size; (void)ws_size;
    const float* x     = (const float*)d_in[0];
    const float* gamma = (const float*)d_in[1];
    const float* beta  = (const float*)d_in[2];
    const float* W1    = (const float*)d_in[3];
    const float* b1    = (const float*)d_in[4];
    const float* W2    = (const float*)d_in[5];
    const float* b2    = (const float*)d_in[6];
    const float* Wc    = (const float*)d_in[7];
    const float* bc    = (const float*)d_in[8];
    float* ws  = (float*)d_ws;
    float* out = (float*)d_out;

    // zero the atomic accumulators: S1..S8 and Asum
    hipMemsetAsync(ws + OFF_S,    0, (size_t)(8*SARR)*sizeof(float), stream);
    hipMemsetAsync(ws + OFF_ASUM, 0, (size_t)SARR*sizeof(float), stream);

    k1_stats   <<<BB*NWD,      128, 0, stream>>>(x, ws);
    k24_powsums<<<BB*NCH*4,    256, 0, stream>>>(x, ws);
    kcomb      <<<BB*NN*NN/256,256, 0, stream>>>(ws);
    k5_rowcorr <<<BB*3,        256, 0, stream>>>(ws);
    k6_anorm   <<<BB,          256, 0, stream>>>(ws);
    k7_ln      <<<BB*NN,       128, 0, stream>>>(gamma, beta, ws);
    k8_gemm    <<<BB*NN/8,     256, 0, stream>>>(W1, b1, ws + OFF_X,    ws + OFF_BUFA, IND);
    k9_prop    <<<BB*16,       256, 0, stream>>>(ws + OFF_ANORM, ws + OFF_BUFA, ws + OFF_BUFB);
    k8_gemm    <<<BB*NN/8,     256, 0, stream>>>(W2, b2, ws + OFF_BUFB, ws + OFF_BUFA, DM);
    k9_prop    <<<BB*16,       256, 0, stream>>>(ws + OFF_ANORM, ws + OFF_BUFA, ws + OFF_BUFB);
    k12_head   <<<BB,          256, 0, stream>>>(ws + OFF_BUFB, Wc, bc, out);
}

// Round 5
// 458.578 us; speedup vs baseline: 3.2822x; 1.1845x over previous
//
#include <hip/hip_runtime.h>
#include <math.h>

#define BB  16
#define TT  1024
#define NN  128
#define WIN 30
#define NWD 498          // number of windows
#define DM  256          // D_MODEL
#define IND 384          // 3*N

#define INV_W (1.0f/498.0f)

#define SARR (BB*NN*NN)  // one moment-sum array

// workspace offsets in floats
#define OFF_A     0                        // rstd/sqrt(29) per (b,w,ch)
#define OFF_G     (OFF_A    + BB*NWD*NN)   // sqrt(30)*mu*a per (b,w,ch)
#define OFF_S     (OFF_G    + BB*NWD*NN)   // S1..S8, 8 arrays of SARR
#define OFF_CM2   (OFF_S    + 8*SARR)
#define OFF_CM4   (OFF_CM2  + SARR)
#define OFF_CM8   (OFF_CM4  + SARR)
#define OFF_ASUM  (OFF_CM8  + SARR)
#define OFF_ANORM (OFF_ASUM + SARR)
#define OFF_X     (OFF_ANORM + SARR)
#define OFF_BUFA  (OFF_X    + BB*NN*IND)
#define OFF_BUFB  (OFF_BUFA + BB*NN*DM)

// ---------------------------------------------------------------- K1: per-window channel stats (single pass)
__global__ __launch_bounds__(128) void k1_stats(const float* __restrict__ x, float* __restrict__ ws) {
    int bw = blockIdx.x;            // b*NWD + w
    int b = bw / NWD, w = bw - b*NWD;
    int n = threadIdx.x;
    int s = w * 2;
    const float* xp = x + ((size_t)(b*TT + s))*NN + n;
    float sum = 0.f, sq = 0.f;
#pragma unroll
    for (int t = 0; t < WIN; ++t) { float v = xp[t*NN]; sum += v; sq = fmaf(v, v, sq); }
    float mean = sum * (1.0f/30.0f);
    float ss = sq - 30.0f*mean*mean;
    float var = fmaxf(ss * (1.0f/29.0f), 1e-8f);
    float r = 1.0f / sqrtf(var);
    float a = r * 0.185695338f;     // fold 1/sqrt(29): corr = P*a_i*a_j - g_i*g_j
    ws[OFF_A + bw*NN + n] = a;
    ws[OFF_G + bw*NN + n] = mean * a * 5.477225575f;   // sqrt(30)*mu*a
}

// ---------------------------------------------------------------- K24: incremental sliding cross-products
// P_w(i,j) updated by 4 rank-1 terms per window; per-window transform + power sums S1..S8.
// grid = b(16) x i-half(2) x j-quarter(4) x wchunk(8) = 1024 blocks.
// Per thread: 2i x 4j = 8 elements -> P[2][4] + S[8][2][4] = 72 persistent floats.
// waves_per_eu(4,4): pin to 128-VGPR budget (live set ~120, no spill), 16 waves/CU.
__global__ __launch_bounds__(256) __attribute__((amdgpu_waves_per_eu(4, 4)))
void k24_inc(const float* __restrict__ x, float* __restrict__ ws) {
    __shared__ __align__(16) float xr[64][NN];   // circular buffer of x rows, slot = t & 63 (32 KB)
    __shared__ __align__(16) float sa[2][NN];    // per-window a, parity-buffered
    __shared__ __align__(16) float sg[2][NN];    // per-window g, parity-buffered
    int bx = blockIdx.x;
    int wc = bx & 7, js = (bx >> 3) & 3, is = (bx >> 5) & 1, b = bx >> 6;
    int w0 = wc * 63, w1 = min(NWD, w0 + 63);
    int tid = threadIdx.x;
    int jg = tid & 7, ig = tid >> 3;
    int i0 = is*64 + ig*2;          // 2 rows (even -> 8B aligned)
    int j0 = js*32 + jg*4;          // 4 cols (16B aligned)

    const float* xb = x + (size_t)b*TT*NN;
    const float* Ab = ws + OFF_A + (size_t)b*NWD*NN;
    const float* Gb = ws + OFF_G + (size_t)b*NWD*NN;

    float P[2][4];
    float S1[2][4], S2[2][4], S3[2][4], S4[2][4], S5[2][4], S6[2][4], S7[2][4], S8[2][4];
#pragma unroll
    for (int p=0;p<2;++p)
#pragma unroll
        for (int q=0;q<4;++q) {
            P[p][q]=0.f;
            S1[p][q]=0.f;S2[p][q]=0.f;S3[p][q]=0.f;S4[p][q]=0.f;
            S5[p][q]=0.f;S6[p][q]=0.f;S7[p][q]=0.f;S8[p][q]=0.f;
        }

    // ---- warmup: stage rows [2w0, 2w0+30) + stats for w0
    for (int idx = tid; idx < WIN*32; idx += 256) {
        int r = idx >> 5, c4 = idx & 31;
        int t = 2*w0 + r;
        *(float4*)&xr[t & 63][c4*4] = ((const float4*)(xb + (size_t)t*NN))[c4];
    }
    {
        int par = w0 & 1;
        if (tid < 32)       *(float4*)&sa[par][tid*4]      = ((const float4*)(Ab + (size_t)w0*NN))[tid];
        else if (tid < 64)  *(float4*)&sg[par][(tid-32)*4] = ((const float4*)(Gb + (size_t)w0*NN))[tid-32];
    }
    __syncthreads();

    // ---- P init for window w0
#pragma unroll 6
    for (int k = 0; k < WIN; ++k) {
        int t = 2*w0 + k;
        float2 xi = *(const float2*)&xr[t & 63][i0];
        float4 xj = *(const float4*)&xr[t & 63][j0];
        float av[2] = {xi.x, xi.y};
        float bv[4] = {xj.x, xj.y, xj.z, xj.w};
#pragma unroll
        for (int p=0;p<2;++p)
#pragma unroll
            for (int q=0;q<4;++q) P[p][q] = fmaf(av[p], bv[q], P[p][q]);
    }

    // ---- per-window moment accumulation (macro-ish lambda)
    auto moments = [&](int par) {
        float2 ai = *(const float2*)&sa[par][i0];
        float2 gi = *(const float2*)&sg[par][i0];
        float4 aj = *(const float4*)&sa[par][j0];
        float4 gj = *(const float4*)&sg[par][j0];
        float av[2] = {ai.x, ai.y};
        float mg[2] = {-gi.x, -gi.y};
        float aw[4] = {aj.x, aj.y, aj.z, aj.w};
        float gw[4] = {gj.x, gj.y, gj.z, gj.w};
#pragma unroll
        for (int p=0;p<2;++p)
#pragma unroll
            for (int q=0;q<4;++q) {
                float aa  = av[p]*aw[q];
                float ngg = mg[p]*gw[q];
                float c   = fmaf(P[p][q], aa, ngg);
                float c2 = c*c;
                float c3 = c2*c;
                float c4 = c2*c2;
                S1[p][q] += c;
                S2[p][q] += c2;
                S3[p][q] += c3;
                S4[p][q] += c4;
                S5[p][q] = fmaf(c4, c,  S5[p][q]);
                S6[p][q] = fmaf(c3, c3, S6[p][q]);
                S7[p][q] = fmaf(c3, c4, S7[p][q]);
                S8[p][q] = fmaf(c4, c4, S8[p][q]);
            }
    };

    moments(w0 & 1);

    // ---- sliding loop: one barrier per window
    for (int w = w0 + 1; w < w1; ++w) {
        // stage the two incoming rows (2w+28, 2w+29) and stats for w (parity w&1)
        if (tid < 64) {
            int r = tid >> 5, c4 = tid & 31;
            int t = 2*w + 28 + r;
            *(float4*)&xr[t & 63][c4*4] = ((const float4*)(xb + (size_t)t*NN))[c4];
        } else if (tid < 96) {
            int c = tid - 64;
            *(float4*)&sa[w & 1][c*4] = ((const float4*)(Ab + (size_t)w*NN))[c];
        } else if (tid < 128) {
            int c = tid - 96;
            *(float4*)&sg[w & 1][c*4] = ((const float4*)(Gb + (size_t)w*NN))[c];
        }
        __syncthreads();
        // P update: -rows 2w-2, 2w-1; +rows 2w+28, 2w+29
        int tr[4] = {2*w - 2, 2*w - 1, 2*w + 28, 2*w + 29};
#pragma unroll
        for (int k = 0; k < 4; ++k) {
            int t = tr[k];
            float sgn = (k < 2) ? -1.0f : 1.0f;
            float2 xi = *(const float2*)&xr[t & 63][i0];
            float4 xj = *(const float4*)&xr[t & 63][j0];
            float av[2] = {sgn*xi.x, sgn*xi.y};
            float bv[4] = {xj.x, xj.y, xj.z, xj.w};
#pragma unroll
            for (int p=0;p<2;++p)
#pragma unroll
                for (int q=0;q<4;++q) P[p][q] = fmaf(av[p], bv[q], P[p][q]);
        }
        moments(w & 1);
    }

    // ---- atomic epilogue
    float* base = ws + OFF_S + (size_t)b*NN*NN;
#pragma unroll
    for (int p=0;p<2;++p)
#pragma unroll
        for (int q=0;q<4;++q) {
            size_t o = (size_t)(i0+p)*NN + (j0+q);
            atomicAdd(base + 0*SARR + o, S1[p][q]);
            atomicAdd(base + 1*SARR + o, S2[p][q]);
            atomicAdd(base + 2*SARR + o, S3[p][q]);
            atomicAdd(base + 3*SARR + o, S4[p][q]);
            atomicAdd(base + 4*SARR + o, S5[p][q]);
            atomicAdd(base + 5*SARR + o, S6[p][q]);
            atomicAdd(base + 6*SARR + o, S7[p][q]);
            atomicAdd(base + 7*SARR + o, S8[p][q]);
        }
}

// ---------------------------------------------------------------- Kcomb: reconstruct centered moments from S1..S8
__global__ __launch_bounds__(256) void kcomb(float* __restrict__ ws) {
    int idx = blockIdx.x*256 + threadIdx.x;   // over BB*NN*NN
    int i = (idx >> 7) & 127, j = idx & 127;
    float cm2, cm4, cm8;
    if (i == j) {
        cm2 = 0.f; cm4 = 0.f; cm8 = 0.f;      // corr diag == 1 every window -> centered == 0
    } else {
        const float* S = ws + OFF_S + idx;
        float e1 = S[0*SARR]*INV_W, e2 = S[1*SARR]*INV_W, e3 = S[2*SARR]*INV_W, e4 = S[3*SARR]*INV_W;
        float e5 = S[4*SARR]*INV_W, e6 = S[5*SARR]*INV_W, e7 = S[6*SARR]*INV_W, e8 = S[7*SARR]*INV_W;
        float m  = e1;
        float m2 = m*m, m3 = m2*m, m4 = m2*m2, m5 = m4*m, m6 = m3*m3, m8 = m4*m4;
        cm2 = e2 - m2;
        cm4 = e4 - 4.f*m*e3 + 6.f*m2*e2 - 3.f*m4;
        cm8 = e8 - 8.f*m*e7 + 28.f*m2*e6 - 56.f*m3*e5 + 70.f*m4*e4
                 - 56.f*m5*e3 + 28.f*m6*e2 - 7.f*m8;
    }
    ws[OFF_CM2 + idx] = cm2;
    ws[OFF_CM4 + idx] = cm4;
    ws[OFF_CM8 + idx] = cm8;
}

// ---------------------------------------------------------------- K5: rowwise_corr per (b, d), accumulate A_sum
__global__ __launch_bounds__(256) void k5_rowcorr(float* __restrict__ ws) {
    __shared__ float Xc[NN][NN+1];
    __shared__ float rmn[NN];
    __shared__ float iden[NN];
    int b = blockIdx.x / 3, di = blockIdx.x % 3;
    const float* cm = ws + (di==0 ? OFF_CM2 : (di==1 ? OFF_CM4 : OFF_CM8)) + (size_t)b*NN*NN;
    int tid = threadIdx.x;
    for (int idx = tid; idx < NN*NN; idx += 256) {
        int n = idx >> 7, f = idx & 127;
        Xc[n][f] = cm[idx];
    }
    __syncthreads();
    if (tid < NN) {
        float s = 0.f;
        for (int f = 0; f < NN; ++f) s += Xc[tid][f];
        rmn[tid] = s * (1.0f/NN);
    }
    __syncthreads();
    for (int idx = tid; idx < NN*NN; idx += 256) {
        int n = idx >> 7, f = idx & 127;
        Xc[n][f] -= rmn[n];
    }
    __syncthreads();
    int n0 = (tid >> 4)*8, m0 = (tid & 15)*8;
    float acc[8][8];
#pragma unroll
    for (int k=0;k<8;++k)
#pragma unroll
        for (int l=0;l<8;++l) acc[k][l] = 0.f;
    for (int f = 0; f < NN; ++f) {
        float an[8], am[8];
#pragma unroll
        for (int k=0;k<8;++k) { an[k] = Xc[n0+k][f]; am[k] = Xc[m0+k][f]; }
#pragma unroll
        for (int k=0;k<8;++k)
#pragma unroll
            for (int l=0;l<8;++l) acc[k][l] = fmaf(an[k], am[l], acc[k][l]);
    }
    if (n0 == m0) {
#pragma unroll
        for (int k=0;k<8;++k) iden[n0+k] = 1.0f/sqrtf(fmaxf(acc[k][k], 1e-8f));
    }
    __syncthreads();
    float* As = ws + OFF_ASUM + (size_t)b*NN*NN;
#pragma unroll
    for (int k=0;k<8;++k)
#pragma unroll
        for (int l=0;l<8;++l) {
            int gi = n0+k, gj = m0+l;
            float v = acc[k][l]*iden[gi]*iden[gj];
            if (gi == gj) v = 1.0f;
            atomicAdd(&As[gi*NN+gj], v);
        }
}

// ---------------------------------------------------------------- K6: symmetrize + normalize adjacency
__global__ __launch_bounds__(256) void k6_anorm(float* __restrict__ ws) {
    __shared__ float As[NN][NN+1];
    __shared__ float dis[NN];
    int b = blockIdx.x;
    const float* Asum = ws + OFF_ASUM + (size_t)b*NN*NN;
    int tid = threadIdx.x;
    for (int idx = tid; idx < NN*NN; idx += 256) {
        int n = idx >> 7, m = idx & 127;
        As[n][m] = (Asum[n*NN+m] + Asum[m*NN+n]) * (1.0f/6.0f);  // mean-of-3 then 0.5*(A+A^T)
    }
    __syncthreads();
    if (tid < NN) {
        float d = 1.0f;                       // +I diag
        for (int m = 0; m < NN; ++m) d += As[tid][m];
        dis[tid] = sqrtf(1.0f / fmaxf(d, 1e-8f));
    }
    __syncthreads();
    float* An = ws + OFF_ANORM + (size_t)b*NN*NN;
    for (int idx = tid; idx < NN*NN; idx += 256) {
        int n = idx >> 7, m = idx & 127;
        float v = As[n][m] + (n==m ? 1.0f : 0.0f);
        An[idx] = v * dis[n] * dis[m];
    }
}

// ---------------------------------------------------------------- K7: build X (concat cm2,4,8) + layernorm
__global__ __launch_bounds__(128) void k7_ln(const float* __restrict__ gamma, const float* __restrict__ beta,
                                             float* __restrict__ ws) {
    __shared__ float red[128];
    int row = blockIdx.x;   // b*NN + n
    int tid = threadIdx.x;
    float v0 = ws[OFF_CM2 + (size_t)row*NN + tid];
    float v1 = ws[OFF_CM4 + (size_t)row*NN + tid];
    float v2 = ws[OFF_CM8 + (size_t)row*NN + tid];
    red[tid] = v0+v1+v2;
    __syncthreads();
    for (int o = 64; o > 0; o >>= 1) { if (tid < o) red[tid] += red[tid+o]; __syncthreads(); }
    float mean = red[0] * (1.0f/IND);
    __syncthreads();
    float d0 = v0-mean, d1 = v1-mean, d2 = v2-mean;
    red[tid] = d0*d0 + d1*d1 + d2*d2;
    __syncthreads();
    for (int o = 64; o > 0; o >>= 1) { if (tid < o) red[tid] += red[tid+o]; __syncthreads(); }
    float rstd = 1.0f / sqrtf(red[0]*(1.0f/IND) + 1e-5f);
    float* X = ws + OFF_X + (size_t)row*IND;
    X[tid]     = d0*rstd*gamma[tid]     + beta[tid];
    X[tid+128] = d1*rstd*gamma[tid+128] + beta[tid+128];
    X[tid+256] = d2*rstd*gamma[tid+256] + beta[tid+256];
}

// ---------------------------------------------------------------- K8: dense (rows x K) @ (K x 256) + bias
__global__ __launch_bounds__(256) void k8_gemm(const float* __restrict__ Wt, const float* __restrict__ bias,
                                               const float* __restrict__ in, float* __restrict__ out, int K) {
    __shared__ float Xs[8][IND];
    int r0 = blockIdx.x * 8;
    int tid = threadIdx.x;
    for (int r = 0; r < 8; ++r)
        for (int c = tid; c < K; c += 256)
            Xs[r][c] = in[(size_t)(r0+r)*K + c];
    __syncthreads();
    float acc[8];
#pragma unroll
    for (int r = 0; r < 8; ++r) acc[r] = bias[tid];
    for (int k = 0; k < K; ++k) {
        float wv = Wt[(size_t)k*DM + tid];
#pragma unroll
        for (int r = 0; r < 8; ++r) acc[r] = fmaf(Xs[r][k], wv, acc[r]);
    }
#pragma unroll
    for (int r = 0; r < 8; ++r) out[(size_t)(r0+r)*DM + tid] = acc[r];
}

// ---------------------------------------------------------------- K9: H = relu(A_norm @ Z)
__global__ __launch_bounds__(256) void k9_prop(const float* __restrict__ Anorm, const float* __restrict__ Zin,
                                               float* __restrict__ out) {
    __shared__ float Ar[8][NN];
    int bx = blockIdx.x;
    int b = bx >> 4, n0 = (bx & 15)*8;
    int tid = threadIdx.x;
    const float* A = Anorm + (size_t)b*NN*NN;
    if (tid < NN) {
#pragma unroll
        for (int r = 0; r < 8; ++r) Ar[r][tid] = A[(n0+r)*NN + tid];
    }
    __syncthreads();
    float acc[8] = {0,0,0,0,0,0,0,0};
    const float* Z = Zin + (size_t)b*NN*DM;
    for (int m = 0; m < NN; ++m) {
        float z = Z[(size_t)m*DM + tid];
#pragma unroll
        for (int r = 0; r < 8; ++r) acc[r] = fmaf(Ar[r][m], z, acc[r]);
    }
    float* O = out + (size_t)b*NN*DM;
#pragma unroll
    for (int r = 0; r < 8; ++r) O[(size_t)(n0+r)*DM + tid] = fmaxf(acc[r], 0.0f);
}

// ---------------------------------------------------------------- K12: mean-pool + sigmoid head
__global__ __launch_bounds__(256) void k12_head(const float* __restrict__ H, const float* __restrict__ Wc,
                                                const float* __restrict__ bc, float* __restrict__ outp) {
    __shared__ float red[256];
    int b = blockIdx.x, tid = threadIdx.x;
    float s = 0.f;
    for (int n = 0; n < NN; ++n) s += H[((size_t)b*NN+n)*DM + tid];
    red[tid] = s * (1.0f/NN) * Wc[tid];
    __syncthreads();
    for (int o = 128; o > 0; o >>= 1) { if (tid < o) red[tid] += red[tid+o]; __syncthreads(); }
    if (tid == 0) outp[b] = 1.0f/(1.0f + expf(-(red[0] + bc[0])));
}

// ----------------------------------------------------------------
extern "C" void kernel_launch(void* const* d_in, const int* in_sizes, int n_in,
                              void* d_out, int out_size, void* d_ws, size_t ws_size,
                              hipStream_t stream) {
    (void)in_sizes; (void)n_in; (void)out_size; (void)ws_size;
    const float* x     = (const float*)d_in[0];
    const float* gamma = (const float*)d_in[1];
    const float* beta  = (const float*)d_in[2];
    const float* W1    = (const float*)d_in[3];
    const float* b1    = (const float*)d_in[4];
    const float* W2    = (const float*)d_in[5];
    const float* b2    = (const float*)d_in[6];
    const float* Wc    = (const float*)d_in[7];
    const float* bc    = (const float*)d_in[8];
    float* ws  = (float*)d_ws;
    float* out = (float*)d_out;

    // zero the atomic accumulators: S1..S8 and Asum
    hipMemsetAsync(ws + OFF_S,    0, (size_t)(8*SARR)*sizeof(float), stream);
    hipMemsetAsync(ws + OFF_ASUM, 0, (size_t)SARR*sizeof(float), stream);

    k1_stats   <<<BB*NWD,      128, 0, stream>>>(x, ws);
    k24_inc    <<<BB*2*4*8,    256, 0, stream>>>(x, ws);
    kcomb      <<<BB*NN*NN/256,256, 0, stream>>>(ws);
    k5_rowcorr <<<BB*3,        256, 0, stream>>>(ws);
    k6_anorm   <<<BB,          256, 0, stream>>>(ws);
    k7_ln      <<<BB*NN,       128, 0, stream>>>(gamma, beta, ws);
    k8_gemm    <<<BB*NN/8,     256, 0, stream>>>(W1, b1, ws + OFF_X,    ws + OFF_BUFA, IND);
    k9_prop    <<<BB*16,       256, 0, stream>>>(ws + OFF_ANORM, ws + OFF_BUFA, ws + OFF_BUFB);
    k8_gemm    <<<BB*NN/8,     256, 0, stream>>>(W2, b2, ws + OFF_BUFB, ws + OFF_BUFA, DM);
    k9_prop    <<<BB*16,       256, 0, stream>>>(ws + OFF_ANORM, ws + OFF_BUFA, ws + OFF_BUFB);
    k12_head   <<<BB,          256, 0, stream>>>(ws + OFF_BUFB, Wc, bc, out);
}

// Round 6
// 379.045 us; speedup vs baseline: 3.9709x; 1.2098x over previous
//
#include <hip/hip_runtime.h>
#include <math.h>

#define BB  16
#define TT  1024
#define NN  128
#define WIN 30
#define NWD 498          // number of windows
#define DM  256          // D_MODEL
#define IND 384          // 3*N
#define GW  9            // windows per staging group in k24

#define INV_W (1.0f/498.0f)

#define SARR (BB*NN*NN)  // one moment-sum array

// workspace offsets in floats
#define OFF_A     0                        // rstd/sqrt(29) per (b,w,ch)
#define OFF_G     (OFF_A    + BB*NWD*NN)   // sqrt(30)*mu*a per (b,w,ch)
#define OFF_S     (OFF_G    + BB*NWD*NN)   // S1..S8, 8 arrays of SARR
#define OFF_CM2   (OFF_S    + 8*SARR)
#define OFF_CM4   (OFF_CM2  + SARR)
#define OFF_CM8   (OFF_CM4  + SARR)
#define OFF_ASUM  (OFF_CM8  + SARR)
#define OFF_ANORM (OFF_ASUM + SARR)
#define OFF_X     (OFF_ANORM + SARR)
#define OFF_BUFA  (OFF_X    + BB*NN*IND)
#define OFF_BUFB  (OFF_BUFA + BB*NN*DM)

// ---------------------------------------------------------------- K1: per-window channel stats (single pass)
__global__ __launch_bounds__(128) void k1_stats(const float* __restrict__ x, float* __restrict__ ws) {
    int bw = blockIdx.x;            // b*NWD + w
    int b = bw / NWD, w = bw - b*NWD;
    int n = threadIdx.x;
    int s = w * 2;
    const float* xp = x + ((size_t)(b*TT + s))*NN + n;
    float sum = 0.f, sq = 0.f;
#pragma unroll
    for (int t = 0; t < WIN; ++t) { float v = xp[t*NN]; sum += v; sq = fmaf(v, v, sq); }
    float mean = sum * (1.0f/30.0f);
    float ss = sq - 30.0f*mean*mean;
    float var = fmaxf(ss * (1.0f/29.0f), 1e-8f);
    float r = 1.0f / sqrtf(var);
    float a = r * 0.185695338f;     // fold 1/sqrt(29): corr = P*a_i*a_j - g_i*g_j
    ws[OFF_A + bw*NN + n] = a;
    ws[OFF_G + bw*NN + n] = mean * a * 5.477225575f;   // sqrt(30)*mu*a
}

// ---------------------------------------------------------------- K24: incremental sliding cross-products
// Symmetric: only 6 slabs {rows 0-63 x cols 0-127, rows 64-127 x cols 64-127}.
// GW windows per staging phase -> 2 barriers per group (14/block) instead of per-window.
// grid = b(16) x slab(6) x wchunk(8) = 768 blocks = 3/CU (LDS 41KB caps at 3).
__global__ __launch_bounds__(256) __attribute__((amdgpu_waves_per_eu(3, 3)))
void k24_inc(const float* __restrict__ x, float* __restrict__ ws) {
    __shared__ __align__(16) float xr[64][NN];   // circular buffer of x rows, slot = t & 63 (32 KB)
    __shared__ __align__(16) float sa[GW][NN];   // per-window a for the group (4.5 KB)
    __shared__ __align__(16) float sg[GW][NN];   // per-window g for the group (4.5 KB)
    int bx = blockIdx.x;
    int wc = bx & 7;                // 8 window chunks of 63
    int slab = (bx >> 3) % 6;
    int b = bx / 48;
    const char IS[6] = {0,0,0,0,1,1};
    const char JS[6] = {0,1,2,3,2,3};
    int is = IS[slab], js = JS[slab];
    int w0 = wc * 63, w1 = min(NWD, w0 + 63);
    int tid = threadIdx.x;
    int jg = tid & 7, ig = tid >> 3;
    int i0 = is*64 + ig*2;          // 2 rows (even -> 8B aligned)
    int j0 = js*32 + jg*4;          // 4 cols (16B aligned)

    const float* xb = x + (size_t)b*TT*NN;
    const float* Ab = ws + OFF_A + (size_t)b*NWD*NN;
    const float* Gb = ws + OFF_G + (size_t)b*NWD*NN;

    float P[2][4];
    float S1[2][4], S2[2][4], S3[2][4], S4[2][4], S5[2][4], S6[2][4], S7[2][4], S8[2][4];
#pragma unroll
    for (int p=0;p<2;++p)
#pragma unroll
        for (int q=0;q<4;++q) {
            P[p][q]=0.f;
            S1[p][q]=0.f;S2[p][q]=0.f;S3[p][q]=0.f;S4[p][q]=0.f;
            S5[p][q]=0.f;S6[p][q]=0.f;S7[p][q]=0.f;S8[p][q]=0.f;
        }

    auto moments = [&](int k) {
        float2 ai = *(const float2*)&sa[k][i0];
        float2 gi = *(const float2*)&sg[k][i0];
        float4 aj = *(const float4*)&sa[k][j0];
        float4 gj = *(const float4*)&sg[k][j0];
        float av[2] = {ai.x, ai.y};
        float mg[2] = {-gi.x, -gi.y};
        float aw[4] = {aj.x, aj.y, aj.z, aj.w};
        float gw[4] = {gj.x, gj.y, gj.z, gj.w};
#pragma unroll
        for (int p=0;p<2;++p)
#pragma unroll
            for (int q=0;q<4;++q) {
                float aa  = av[p]*aw[q];
                float ngg = mg[p]*gw[q];
                float c   = fmaf(P[p][q], aa, ngg);
                float c2 = c*c;
                float c3 = c2*c;
                float c4 = c2*c2;
                S1[p][q] += c;
                S2[p][q] += c2;
                S3[p][q] += c3;
                S4[p][q] += c4;
                S5[p][q] = fmaf(c4, c,  S5[p][q]);
                S6[p][q] = fmaf(c3, c3, S6[p][q]);
                S7[p][q] = fmaf(c3, c4, S7[p][q]);
                S8[p][q] = fmaf(c4, c4, S8[p][q]);
            }
    };

    int rlo = 2*w0;                 // first row not yet staged
    for (int wg = w0; wg < w1; wg += GW) {
        int m = min(GW, w1 - wg);
        __syncthreads();            // prior group's compute done reading xr/sa/sg
        // stage new x rows [rlo, rhi]
        int rhi = 2*(wg + m - 1) + 29;
        int nr = rhi - rlo + 1;
        for (int idx = tid; idx < nr*32; idx += 256) {
            int r = idx >> 5, c4 = idx & 31;
            int t = rlo + r;
            *(float4*)&xr[t & 63][c4*4] = ((const float4*)(xb + (size_t)t*NN))[c4];
        }
        // stage stats for windows wg..wg+m-1
        for (int idx = tid; idx < m*32; idx += 256) {
            int k = idx >> 5, c4 = idx & 31;
            *(float4*)&sa[k][c4*4] = ((const float4*)(Ab + (size_t)(wg+k)*NN))[c4];
        }
        for (int idx = tid; idx < m*32; idx += 256) {
            int k = idx >> 5, c4 = idx & 31;
            *(float4*)&sg[k][c4*4] = ((const float4*)(Gb + (size_t)(wg+k)*NN))[c4];
        }
        rlo = rhi + 1;
        __syncthreads();            // staging visible

        int kstart = 0;
        if (wg == w0) {
            // P init for window w0 over rows 2w0..2w0+29
#pragma unroll 6
            for (int k = 0; k < WIN; ++k) {
                int t = 2*w0 + k;
                float2 xi = *(const float2*)&xr[t & 63][i0];
                float4 xj = *(const float4*)&xr[t & 63][j0];
                float av[2] = {xi.x, xi.y};
                float bv[4] = {xj.x, xj.y, xj.z, xj.w};
#pragma unroll
                for (int p=0;p<2;++p)
#pragma unroll
                    for (int q=0;q<4;++q) P[p][q] = fmaf(av[p], bv[q], P[p][q]);
            }
            moments(0);
            kstart = 1;
        }
        for (int k = kstart; k < m; ++k) {
            int w = wg + k;
            // P update: -rows 2w-2, 2w-1; +rows 2w+28, 2w+29
            int tr[4] = {2*w - 2, 2*w - 1, 2*w + 28, 2*w + 29};
#pragma unroll
            for (int kk = 0; kk < 4; ++kk) {
                int t = tr[kk];
                float sgn = (kk < 2) ? -1.0f : 1.0f;
                float2 xi = *(const float2*)&xr[t & 63][i0];
                float4 xj = *(const float4*)&xr[t & 63][j0];
                float av[2] = {sgn*xi.x, sgn*xi.y};
                float bv[4] = {xj.x, xj.y, xj.z, xj.w};
#pragma unroll
                for (int p=0;p<2;++p)
#pragma unroll
                    for (int q=0;q<4;++q) P[p][q] = fmaf(av[p], bv[q], P[p][q]);
            }
            moments(k);
        }
    }

    // ---- atomic epilogue
    float* base = ws + OFF_S + (size_t)b*NN*NN;
#pragma unroll
    for (int p=0;p<2;++p)
#pragma unroll
        for (int q=0;q<4;++q) {
            size_t o = (size_t)(i0+p)*NN + (j0+q);
            atomicAdd(base + 0*SARR + o, S1[p][q]);
            atomicAdd(base + 1*SARR + o, S2[p][q]);
            atomicAdd(base + 2*SARR + o, S3[p][q]);
            atomicAdd(base + 3*SARR + o, S4[p][q]);
            atomicAdd(base + 4*SARR + o, S5[p][q]);
            atomicAdd(base + 5*SARR + o, S6[p][q]);
            atomicAdd(base + 6*SARR + o, S7[p][q]);
            atomicAdd(base + 7*SARR + o, S8[p][q]);
        }
}

// ---------------------------------------------------------------- Kcomb: reconstruct centered moments from S1..S8
// S is symmetric; k24 only filled i<64 (all j) and i>=64,j>=64 -> read (lo,hi) ordered entry.
__global__ __launch_bounds__(256) void kcomb(float* __restrict__ ws) {
    int idx = blockIdx.x*256 + threadIdx.x;   // over BB*NN*NN
    int i = (idx >> 7) & 127, j = idx & 127;
    float cm2, cm4, cm8;
    if (i == j) {
        cm2 = 0.f; cm4 = 0.f; cm8 = 0.f;      // corr diag == 1 every window -> centered == 0
    } else {
        int lo = min(i, j), hi = max(i, j);
        int bbase = idx & ~(NN*NN - 1);
        const float* S = ws + OFF_S + bbase + lo*NN + hi;
        float e1 = S[0*SARR]*INV_W, e2 = S[1*SARR]*INV_W, e3 = S[2*SARR]*INV_W, e4 = S[3*SARR]*INV_W;
        float e5 = S[4*SARR]*INV_W, e6 = S[5*SARR]*INV_W, e7 = S[6*SARR]*INV_W, e8 = S[7*SARR]*INV_W;
        float m  = e1;
        float m2 = m*m, m3 = m2*m, m4 = m2*m2, m5 = m4*m, m6 = m3*m3, m8 = m4*m4;
        cm2 = e2 - m2;
        cm4 = e4 - 4.f*m*e3 + 6.f*m2*e2 - 3.f*m4;
        cm8 = e8 - 8.f*m*e7 + 28.f*m2*e6 - 56.f*m3*e5 + 70.f*m4*e4
                 - 56.f*m5*e3 + 28.f*m6*e2 - 7.f*m8;
    }
    ws[OFF_CM2 + idx] = cm2;
    ws[OFF_CM4 + idx] = cm4;
    ws[OFF_CM8 + idx] = cm8;
}

// ---------------------------------------------------------------- K5: rowwise_corr per (b, d, j-half), accumulate A_sum
__global__ __launch_bounds__(256) void k5_rowcorr(float* __restrict__ ws) {
    __shared__ float Xc[NN][NN+1];
    __shared__ float rmn[NN];
    __shared__ float iden[NN];
    int t = blockIdx.x;
    int jh = t & 1; int di = (t >> 1) % 3; int b = t / 6;
    const float* cm = ws + (di==0 ? OFF_CM2 : (di==1 ? OFF_CM4 : OFF_CM8)) + (size_t)b*NN*NN;
    int tid = threadIdx.x;
    for (int idx = tid; idx < NN*NN; idx += 256) {
        int n = idx >> 7, f = idx & 127;
        Xc[n][f] = cm[idx];
    }
    __syncthreads();
    if (tid < NN) {
        float s = 0.f;
        for (int f = 0; f < NN; ++f) s += Xc[tid][f];
        rmn[tid] = s * (1.0f/NN);
    }
    __syncthreads();
    for (int idx = tid; idx < NN*NN; idx += 256) {
        int n = idx >> 7, f = idx & 127;
        Xc[n][f] -= rmn[n];
    }
    __syncthreads();
    if (tid < NN) {
        float s = 0.f;
        for (int f = 0; f < NN; ++f) { float v = Xc[tid][f]; s = fmaf(v, v, s); }
        iden[tid] = 1.0f/sqrtf(fmaxf(s, 1e-8f));
    }
    __syncthreads();
    // output: all 128 rows x 64 cols (jh). 16x16 thread grid, 8x4 per thread.
    int n0 = (tid >> 4)*8, m0 = jh*64 + (tid & 15)*4;
    float acc[8][4];
#pragma unroll
    for (int k=0;k<8;++k)
#pragma unroll
        for (int l=0;l<4;++l) acc[k][l] = 0.f;
    for (int f = 0; f < NN; ++f) {
        float an[8], am[4];
#pragma unroll
        for (int k=0;k<8;++k) an[k] = Xc[n0+k][f];
#pragma unroll
        for (int l=0;l<4;++l) am[l] = Xc[m0+l][f];
#pragma unroll
        for (int k=0;k<8;++k)
#pragma unroll
            for (int l=0;l<4;++l) acc[k][l] = fmaf(an[k], am[l], acc[k][l]);
    }
    float* As = ws + OFF_ASUM + (size_t)b*NN*NN;
#pragma unroll
    for (int k=0;k<8;++k)
#pragma unroll
        for (int l=0;l<4;++l) {
            int gi = n0+k, gj = m0+l;
            float v = acc[k][l]*iden[gi]*iden[gj];
            if (gi == gj) v = 1.0f;
            atomicAdd(&As[gi*NN+gj], v);
        }
}

// ---------------------------------------------------------------- K6: symmetrize + normalize adjacency
__global__ __launch_bounds__(256) void k6_anorm(float* __restrict__ ws) {
    __shared__ float As[NN][NN+1];
    __shared__ float dis[NN];
    int b = blockIdx.x;
    const float* Asum = ws + OFF_ASUM + (size_t)b*NN*NN;
    int tid = threadIdx.x;
    for (int idx = tid; idx < NN*NN; idx += 256) {
        int n = idx >> 7, m = idx & 127;
        As[n][m] = (Asum[n*NN+m] + Asum[m*NN+n]) * (1.0f/6.0f);  // mean-of-3 then 0.5*(A+A^T)
    }
    __syncthreads();
    if (tid < NN) {
        float d = 1.0f;                       // +I diag
        for (int m = 0; m < NN; ++m) d += As[tid][m];
        dis[tid] = sqrtf(1.0f / fmaxf(d, 1e-8f));
    }
    __syncthreads();
    float* An = ws + OFF_ANORM + (size_t)b*NN*NN;
    for (int idx = tid; idx < NN*NN; idx += 256) {
        int n = idx >> 7, m = idx & 127;
        float v = As[n][m] + (n==m ? 1.0f : 0.0f);
        An[idx] = v * dis[n] * dis[m];
    }
}

// ---------------------------------------------------------------- K7: build X (concat cm2,4,8) + layernorm
__global__ __launch_bounds__(128) void k7_ln(const float* __restrict__ gamma, const float* __restrict__ beta,
                                             float* __restrict__ ws) {
    __shared__ float red[128];
    int row = blockIdx.x;   // b*NN + n
    int tid = threadIdx.x;
    float v0 = ws[OFF_CM2 + (size_t)row*NN + tid];
    float v1 = ws[OFF_CM4 + (size_t)row*NN + tid];
    float v2 = ws[OFF_CM8 + (size_t)row*NN + tid];
    red[tid] = v0+v1+v2;
    __syncthreads();
    for (int o = 64; o > 0; o >>= 1) { if (tid < o) red[tid] += red[tid+o]; __syncthreads(); }
    float mean = red[0] * (1.0f/IND);
    __syncthreads();
    float d0 = v0-mean, d1 = v1-mean, d2 = v2-mean;
    red[tid] = d0*d0 + d1*d1 + d2*d2;
    __syncthreads();
    for (int o = 64; o > 0; o >>= 1) { if (tid < o) red[tid] += red[tid+o]; __syncthreads(); }
    float rstd = 1.0f / sqrtf(red[0]*(1.0f/IND) + 1e-5f);
    float* X = ws + OFF_X + (size_t)row*IND;
    X[tid]     = d0*rstd*gamma[tid]     + beta[tid];
    X[tid+128] = d1*rstd*gamma[tid+128] + beta[tid+128];
    X[tid+256] = d2*rstd*gamma[tid+256] + beta[tid+256];
}

// ---------------------------------------------------------------- K8: dense (rows x K) @ (K x 256) + bias
__global__ __launch_bounds__(256) void k8_gemm(const float* __restrict__ Wt, const float* __restrict__ bias,
                                               const float* __restrict__ in, float* __restrict__ out, int K) {
    __shared__ float Xs[8][IND];
    int r0 = blockIdx.x * 8;
    int tid = threadIdx.x;
    for (int r = 0; r < 8; ++r)
        for (int c = tid; c < K; c += 256)
            Xs[r][c] = in[(size_t)(r0+r)*K + c];
    __syncthreads();
    float acc[8];
#pragma unroll
    for (int r = 0; r < 8; ++r) acc[r] = bias[tid];
    for (int k = 0; k < K; ++k) {
        float wv = Wt[(size_t)k*DM + tid];
#pragma unroll
        for (int r = 0; r < 8; ++r) acc[r] = fmaf(Xs[r][k], wv, acc[r]);
    }
#pragma unroll
    for (int r = 0; r < 8; ++r) out[(size_t)(r0+r)*DM + tid] = acc[r];
}

// ---------------------------------------------------------------- K9: H = relu(A_norm @ Z)
__global__ __launch_bounds__(256) void k9_prop(const float* __restrict__ Anorm, const float* __restrict__ Zin,
                                               float* __restrict__ out) {
    __shared__ float Ar[8][NN];
    int bx = blockIdx.x;
    int b = bx >> 4, n0 = (bx & 15)*8;
    int tid = threadIdx.x;
    const float* A = Anorm + (size_t)b*NN*NN;
    if (tid < NN) {
#pragma unroll
        for (int r = 0; r < 8; ++r) Ar[r][tid] = A[(n0+r)*NN + tid];
    }
    __syncthreads();
    float acc[8] = {0,0,0,0,0,0,0,0};
    const float* Z = Zin + (size_t)b*NN*DM;
    for (int m = 0; m < NN; ++m) {
        float z = Z[(size_t)m*DM + tid];
#pragma unroll
        for (int r = 0; r < 8; ++r) acc[r] = fmaf(Ar[r][m], z, acc[r]);
    }
    float* O = out + (size_t)b*NN*DM;
#pragma unroll
    for (int r = 0; r < 8; ++r) O[(size_t)(n0+r)*DM + tid] = fmaxf(acc[r], 0.0f);
}

// ---------------------------------------------------------------- K12: mean-pool + sigmoid head
__global__ __launch_bounds__(256) void k12_head(const float* __restrict__ H, const float* __restrict__ Wc,
                                                const float* __restrict__ bc, float* __restrict__ outp) {
    __shared__ float red[256];
    int b = blockIdx.x, tid = threadIdx.x;
    float s = 0.f;
    for (int n = 0; n < NN; ++n) s += H[((size_t)b*NN+n)*DM + tid];
    red[tid] = s * (1.0f/NN) * Wc[tid];
    __syncthreads();
    for (int o = 128; o > 0; o >>= 1) { if (tid < o) red[tid] += red[tid+o]; __syncthreads(); }
    if (tid == 0) outp[b] = 1.0f/(1.0f + expf(-(red[0] + bc[0])));
}

// ----------------------------------------------------------------
extern "C" void kernel_launch(void* const* d_in, const int* in_sizes, int n_in,
                              void* d_out, int out_size, void* d_ws, size_t ws_size,
                              hipStream_t stream) {
    (void)in_sizes; (void)n_in; (void)out_size; (void)ws_size;
    const float* x     = (const float*)d_in[0];
    const float* gamma = (const float*)d_in[1];
    const float* beta  = (const float*)d_in[2];
    const float* W1    = (const float*)d_in[3];
    const float* b1    = (const float*)d_in[4];
    const float* W2    = (const float*)d_in[5];
    const float* b2    = (const float*)d_in[6];
    const float* Wc    = (const float*)d_in[7];
    const float* bc    = (const float*)d_in[8];
    float* ws  = (float*)d_ws;
    float* out = (float*)d_out;

    // zero the atomic accumulators: S1..S8 and Asum
    hipMemsetAsync(ws + OFF_S,    0, (size_t)(8*SARR)*sizeof(float), stream);
    hipMemsetAsync(ws + OFF_ASUM, 0, (size_t)SARR*sizeof(float), stream);

    k1_stats   <<<BB*NWD,      128, 0, stream>>>(x, ws);
    k24_inc    <<<BB*6*8,      256, 0, stream>>>(x, ws);
    kcomb      <<<BB*NN*NN/256,256, 0, stream>>>(ws);
    k5_rowcorr <<<BB*3*2,      256, 0, stream>>>(ws);
    k6_anorm   <<<BB,          256, 0, stream>>>(ws);
    k7_ln      <<<BB*NN,       128, 0, stream>>>(gamma, beta, ws);
    k8_gemm    <<<BB*NN/8,     256, 0, stream>>>(W1, b1, ws + OFF_X,    ws + OFF_BUFA, IND);
    k9_prop    <<<BB*16,       256, 0, stream>>>(ws + OFF_ANORM, ws + OFF_BUFA, ws + OFF_BUFB);
    k8_gemm    <<<BB*NN/8,     256, 0, stream>>>(W2, b2, ws + OFF_BUFB, ws + OFF_BUFA, DM);
    k9_prop    <<<BB*16,       256, 0, stream>>>(ws + OFF_ANORM, ws + OFF_BUFA, ws + OFF_BUFB);
    k12_head   <<<BB,          256, 0, stream>>>(ws + OFF_BUFB, Wc, bc, out);
}